// Round 1
// 150.005 us; speedup vs baseline: 1.0513x; 1.0513x over previous
//
#include <hip/hip_runtime.h>
#include <stdint.h>

#define N_TOK 4096
#define DIM   512
#define BATCH 4
#define BN    (BATCH * N_TOK)
#define JSPLIT 8
#define IPW   64                      // i-rows per wave (A resident in regs)
#define IPB   256                     // i-rows per block (4 waves)
#define NG    (N_TOK / JSPLIT / 16)   // 32 j-groups of 16 per slice

typedef __attribute__((ext_vector_type(4))) float f32x4;
typedef __attribute__((ext_vector_type(8))) int   i32x8;

typedef const __attribute__((address_space(1))) uint32_t* gptr_t;
typedef __attribute__((address_space(3))) uint32_t* lptr_t;

__device__ __forceinline__ float sumsq8(uint lo, uint hi) {
    float s = 0.f, f;
    f = __builtin_amdgcn_cvt_f32_fp8((int)lo, 0); s = fmaf(f, f, s);
    f = __builtin_amdgcn_cvt_f32_fp8((int)lo, 1); s = fmaf(f, f, s);
    f = __builtin_amdgcn_cvt_f32_fp8((int)lo, 2); s = fmaf(f, f, s);
    f = __builtin_amdgcn_cvt_f32_fp8((int)lo, 3); s = fmaf(f, f, s);
    f = __builtin_amdgcn_cvt_f32_fp8((int)hi, 0); s = fmaf(f, f, s);
    f = __builtin_amdgcn_cvt_f32_fp8((int)hi, 1); s = fmaf(f, f, s);
    f = __builtin_amdgcn_cvt_f32_fp8((int)hi, 2); s = fmaf(f, f, s);
    f = __builtin_amdgcn_cvt_f32_fp8((int)hi, 3); s = fmaf(f, f, s);
    return s;
}

// ---------- prep: fp8 convert -> fb (row-major) + fbT (B-operand, LDS-image layout)
//            + per-row sumsq of QUANTIZED values (diag d_ii ~ 0 matches ref k_ii=1).
// NEW fbT layout per 16-row group (8KB) — the exact LDS image the entropy kernel
// stages with global_load_lds (linear dest) and reads conflict-free:
//   byte = kk*2048 + half*1024 + lane*16 + w8p*8,  lane = q*16 + r
//   content = row r, K bytes [kk*128 + q*32 + (half*2+w8p)*8 .. +8)
// => ds_read_b128 at lane*16 is stride-16B contiguous across the wave (0 conflicts),
//    and staging is a pure linear 1KB-per-instruction copy.
__global__ __launch_bounds__(256) void prep_kernel(
    const float* __restrict__ feat, uint8_t* __restrict__ fb,
    uint8_t* __restrict__ fbT, float* __restrict__ sq)
{
    __shared__ __align__(16) long lt[1024];        // [chunk c 0..63][row16], swizzled
    const int t = threadIdx.x;
    const int row16 = t >> 4, seg = t & 15;
    const size_t grp = blockIdx.x;
    const size_t row = grp * 16 + row16;

    const float4* src = (const float4*)(feat + row * DIM + seg * 32);
    uint32_t wd[8];
    float s = 0.f;
#pragma unroll
    for (int i = 0; i < 4; ++i) {
        float4 a = src[2 * i], b = src[2 * i + 1];
        uint lo = (uint)__builtin_amdgcn_cvt_pk_fp8_f32(a.x, a.y, 0, false);
        lo      = (uint)__builtin_amdgcn_cvt_pk_fp8_f32(a.z, a.w, (int)lo, true);
        uint hi = (uint)__builtin_amdgcn_cvt_pk_fp8_f32(b.x, b.y, 0, false);
        hi      = (uint)__builtin_amdgcn_cvt_pk_fp8_f32(b.z, b.w, (int)hi, true);
        wd[2 * i] = lo; wd[2 * i + 1] = hi;
        s += sumsq8(lo, hi);
    }

    uint4* dst = (uint4*)(fb + row * DIM + seg * 32);
    uint4 o0; o0.x = wd[0]; o0.y = wd[1]; o0.z = wd[2]; o0.w = wd[3];
    uint4 o1; o1.x = wd[4]; o1.y = wd[5]; o1.z = wd[6]; o1.w = wd[7];
    dst[0] = o0; dst[1] = o1;

#pragma unroll
    for (int i = 0; i < 4; ++i) {
        int c = seg * 4 + i;                       // 8B chunk of this row
        long d = ((long)(unsigned)wd[2 * i + 1] << 32) | (unsigned)wd[2 * i];
        lt[c * 16 + ((row16 + c) & 15)] = d;
    }

#pragma unroll
    for (int m = 1; m < 16; m <<= 1) s += __shfl_xor(s, m);
    if (seg == 0) sq[row] = s;

    __syncthreads();
    long* ot = (long*)(fbT + grp * 8192);
#pragma unroll
    for (int i = 0; i < 4; ++i) {
        int p    = t + i * 256;                    // output long index, coalesced
        int kk   = p >> 8;                         // 128-wide K chunk
        int rem  = p & 255;
        int half = rem >> 7;                       // lo/hi 16B of the lane's 32B
        int l6   = (rem >> 1) & 63;                // dest lane
        int qq   = l6 >> 4;                        // 32-elem scale block
        int r    = l6 & 15;                        // j row in group
        int w8   = half * 2 + (p & 1);             // 8B word within lane's 32B
        int c    = kk * 16 + qq * 4 + w8;          // source 8B chunk in row
        ot[p] = lt[c * 16 + ((r + c) & 15)];
    }
}

// ---------- entropy: MX-scaled fp8 MFMA (K=128), register A + LDS-staged B ----------
// Flat 512-block grid (2/CU), XCD-swizzled (combo = flat&31 => jh = XCD id, so the
// 16 blocks sharing a B slice land on one XCD's L2).
// B is staged ONCE per block into LDS (was: each of 4 waves streamed it privately
// from L2 => 64KB/CU/group ~ 1170cyc, as costly as the 1106cyc of MFMAs). T3 minimal
// 2-phase double-buffer: stage g+1 (global_load_lds w16, linear dest) -> compute g
// -> barrier (compiler's vmcnt(0) drain = the wait; stage-to-use distance = one full
// compute phase > HBM latency). ds_read_b128 at lane*16: conflict-free.
__global__ __launch_bounds__(256, 2) void entropy_kernel(
    const uint8_t* __restrict__ fb, const uint8_t* __restrict__ fbT,
    const float* __restrict__ sq, const float* __restrict__ temp,
    float* __restrict__ Sp, float* __restrict__ Tp)
{
    __shared__ uint4 Bs[2][512];                   // 2 x 8KB double buffer
    const int t    = threadIdx.x;
    const int w    = t >> 6;
    const int lane = t & 63;
    const int q    = lane >> 4;
    const int c16  = lane & 15;
    const int lbo  = lane * 16;

    const int flat  = blockIdx.x;
    const int combo = flat & 31;
    const int batch = combo >> 3;
    const int jh    = combo & 7;
    const int iblk  = flat >> 5;
    const int iw    = iblk * IPB + w * IPW;
    const size_t rowbase = (size_t)batch * N_TOK;

    const float tau    = temp[0];
    const float inv2t2 = 0.5f / (tau * tau);
    const float cg     = 1.0f / (tau * tau);

    // A fragments: 4 strips x 4 K-chunks x 32B = 128 regs, loop-invariant
    i32x8 afrag[4][4];
#pragma unroll
    for (int s = 0; s < 4; ++s) {
        const uint4* ap = (const uint4*)(fb + (rowbase + iw + s * 16 + c16) * DIM);
#pragma unroll
        for (int kk = 0; kk < 4; ++kk) {
            uint4 lo = ap[kk * 8 + q * 2];
            uint4 hi = ap[kk * 8 + q * 2 + 1];
            i32x8 v = {(int)lo.x, (int)lo.y, (int)lo.z, (int)lo.w,
                       (int)hi.x, (int)hi.y, (int)hi.z, (int)hi.w};
            afrag[s][kk] = v;
        }
    }
    float pi[4][4];
#pragma unroll
    for (int s = 0; s < 4; ++s)
#pragma unroll
        for (int r = 0; r < 4; ++r)
            pi[s][r] = -sq[rowbase + iw + s * 16 + q * 4 + r] * inv2t2;

    float S[4][4], T[4][4];
#pragma unroll
    for (int s = 0; s < 4; ++s)
#pragma unroll
        for (int r = 0; r < 4; ++r) { S[s][r] = 0.f; T[s][r] = 0.f; }

    const uint8_t* bgbase = fbT
        + ((size_t)batch * (N_TOK / 16) + (size_t)jh * NG) * 8192;
    const float* sqj = sq + rowbase + jh * (N_TOK / JSPLIT) + c16;

    // prologue: stage group 0 (wave w copies its linear 2KB: 2 x 1KB instructions)
    {
        const uint8_t* gs = bgbase + w * 2048 + lbo;
        uint8_t* ld = (uint8_t*)Bs[0] + w * 2048;
        __builtin_amdgcn_global_load_lds((gptr_t)(const void*)gs,
                                         (lptr_t)(void*)ld, 16, 0, 0);
        __builtin_amdgcn_global_load_lds((gptr_t)(const void*)(gs + 1024),
                                         (lptr_t)(void*)(ld + 1024), 16, 0, 0);
    }
    __syncthreads();                               // vmcnt(0) drain lands group 0

    int cur = 0;
    for (int g = 0; g < NG; ++g) {
        if (g + 1 < NG) {                          // stage next group into other buf
            const uint8_t* gs = bgbase + (size_t)(g + 1) * 8192 + w * 2048 + lbo;
            uint8_t* ld = (uint8_t*)Bs[cur ^ 1] + w * 2048;
            __builtin_amdgcn_global_load_lds((gptr_t)(const void*)gs,
                                             (lptr_t)(void*)ld, 16, 0, 0);
            __builtin_amdgcn_global_load_lds((gptr_t)(const void*)(gs + 1024),
                                             (lptr_t)(void*)(ld + 1024), 16, 0, 0);
        }
        float pj = -sqj[(size_t)g * 16] * inv2t2;
        const uint8_t* bs = (const uint8_t*)Bs[cur];
        f32x4 acc[4] = {{0,0,0,0},{0,0,0,0},{0,0,0,0},{0,0,0,0}};
#pragma unroll
        for (int kk = 0; kk < 4; ++kk) {
            uint4 lo = *(const uint4*)(bs + kk * 2048 + lbo);
            uint4 hi = *(const uint4*)(bs + kk * 2048 + 1024 + lbo);
            i32x8 b = {(int)lo.x, (int)lo.y, (int)lo.z, (int)lo.w,
                       (int)hi.x, (int)hi.y, (int)hi.z, (int)hi.w};
            acc[0] = __builtin_amdgcn_mfma_scale_f32_16x16x128_f8f6f4(afrag[0][kk], b, acc[0], 0, 0, 0, 127, 0, 127);
            acc[1] = __builtin_amdgcn_mfma_scale_f32_16x16x128_f8f6f4(afrag[1][kk], b, acc[1], 0, 0, 0, 127, 0, 127);
            acc[2] = __builtin_amdgcn_mfma_scale_f32_16x16x128_f8f6f4(afrag[2][kk], b, acc[2], 0, 0, 0, 127, 0, 127);
            acc[3] = __builtin_amdgcn_mfma_scale_f32_16x16x128_f8f6f4(afrag[3][kk], b, acc[3], 0, 0, 0, 127, 0, 127);
        }
        float m = -1e30f;
#pragma unroll
        for (int s = 0; s < 4; ++s)
#pragma unroll
            for (int r = 0; r < 4; ++r) {          // e in place of acc (dead after)
                acc[s][r] = fmaf(acc[s][r], cg, pi[s][r] + pj);
                m = fmaxf(m, acc[s][r]);
            }
        if (m > -110.0f) {                         // only diagonal-adjacent groups
#pragma unroll
            for (int s = 0; s < 4; ++s)
#pragma unroll
                for (int r = 0; r < 4; ++r) {
                    float ee = fminf(acc[s][r], 0.f);
                    float k  = __expf(ee);
                    S[s][r] += k;
                    T[s][r]  = fmaf(k, ee, T[s][r]);
                }
        }
        __syncthreads();                           // drains stage(g+1) + read done
        cur ^= 1;
    }

    // reduce over the 16 j-columns (c16 lanes)
#pragma unroll
    for (int m = 1; m < 16; m <<= 1)
#pragma unroll
        for (int s = 0; s < 4; ++s)
#pragma unroll
            for (int r = 0; r < 4; ++r) {
                S[s][r] += __shfl_xor(S[s][r], m);
                T[s][r] += __shfl_xor(T[s][r], m);
            }

    if (c16 == 0) {
#pragma unroll
        for (int s = 0; s < 4; ++s)
#pragma unroll
            for (int r = 0; r < 4; ++r) {
                size_t idx = (size_t)jh * BN + rowbase + iw + s * 16 + q * 4 + r;
                Sp[idx] = S[s][r];
                Tp[idx] = T[s][r];
            }
    }
}

// ---------- finalize: combine partials, entropy -> sigmoid -> scale features ----------
__global__ __launch_bounds__(256) void finalize_kernel(
    const float* __restrict__ feat, const float* __restrict__ Sp,
    const float* __restrict__ Tp, const float* __restrict__ tgt,
    const float* __restrict__ temp, float* __restrict__ out)
{
    int row  = (blockIdx.x << 2) + (threadIdx.x >> 6);   // global row 0..BN-1
    int lane = threadIdx.x & 63;
    float S = 0.0f, T = 0.0f;
#pragma unroll
    for (int j = 0; j < JSPLIT; ++j) {
        S += Sp[(size_t)j * BN + row];
        T += Tp[(size_t)j * BN + row];
    }
    float tau = temp[0];
    float E  = __logf(S) - T / S;                  // entropy (sans +1e-6, bias<4e-3)
    float cs = 1.0f / (1.0f + __expf((E - tgt[0]) / tau));

    const float4* F4 = (const float4*)(feat + (size_t)row * DIM);
    float4*       O4 = (float4*)(out + (size_t)row * DIM);
    float4 v0 = F4[lane], v1 = F4[lane + 64];
    v0.x *= cs; v0.y *= cs; v0.z *= cs; v0.w *= cs;
    v1.x *= cs; v1.y *= cs; v1.z *= cs; v1.w *= cs;
    O4[lane] = v0; O4[lane + 64] = v1;
    if (lane == 0) out[(size_t)BN * DIM + row] = cs;
}

extern "C" void kernel_launch(void* const* d_in, const int* in_sizes, int n_in,
                              void* d_out, int out_size, void* d_ws, size_t ws_size,
                              hipStream_t stream) {
    const float* feat = (const float*)d_in[0];
    const float* tgt  = (const float*)d_in[7];   // target_entropy
    const float* temp = (const float*)d_in[8];   // temperature
    float* out = (float*)d_out;

    char* ws = (char*)d_ws;
    uint8_t* fb  = (uint8_t*)ws;                               // fp8 row-major, 8.4MB
    uint8_t* fbT = fb + (size_t)BN * DIM;                      // fp8 B-layout (LDS image), 8.4MB
    float*   sq  = (float*)(fbT + (size_t)BN * DIM);           // quantized row sumsq
    float*   Sp  = sq + BN;                                    // partial S, JSPLIT slices
    float*   Tp  = Sp + (size_t)JSPLIT * BN;                   // partial T, JSPLIT slices

    prep_kernel<<<dim3(BN / 16), dim3(256), 0, stream>>>(feat, fb, fbT, sq);
    entropy_kernel<<<dim3((N_TOK / IPB) * BATCH * JSPLIT), dim3(256), 0, stream>>>(fb, fbT, sq, temp, Sp, Tp);
    finalize_kernel<<<dim3(BN / 4), dim3(256), 0, stream>>>(feat, Sp, Tp, tgt, temp, out);
}

// Round 2
// 148.379 us; speedup vs baseline: 1.0628x; 1.0110x over previous
//
#include <hip/hip_runtime.h>
#include <stdint.h>

#define N_TOK 4096
#define DIM   512
#define BATCH 4
#define BN    (BATCH * N_TOK)
#define JSPLIT 8
#define IPW   64                      // i-rows per wave (A resident in regs)
#define IPB   256                     // i-rows per block (4 waves)
#define NG    (N_TOK / JSPLIT / 16)   // 32 j-groups of 16 per slice

typedef __attribute__((ext_vector_type(4))) float f32x4;
typedef __attribute__((ext_vector_type(8))) int   i32x8;

typedef const __attribute__((address_space(1))) uint32_t* gptr_t;
typedef __attribute__((address_space(3))) uint32_t* lptr_t;

__device__ __forceinline__ float sumsq8(uint lo, uint hi) {
    float s = 0.f, f;
    f = __builtin_amdgcn_cvt_f32_fp8((int)lo, 0); s = fmaf(f, f, s);
    f = __builtin_amdgcn_cvt_f32_fp8((int)lo, 1); s = fmaf(f, f, s);
    f = __builtin_amdgcn_cvt_f32_fp8((int)lo, 2); s = fmaf(f, f, s);
    f = __builtin_amdgcn_cvt_f32_fp8((int)lo, 3); s = fmaf(f, f, s);
    f = __builtin_amdgcn_cvt_f32_fp8((int)hi, 0); s = fmaf(f, f, s);
    f = __builtin_amdgcn_cvt_f32_fp8((int)hi, 1); s = fmaf(f, f, s);
    f = __builtin_amdgcn_cvt_f32_fp8((int)hi, 2); s = fmaf(f, f, s);
    f = __builtin_amdgcn_cvt_f32_fp8((int)hi, 3); s = fmaf(f, f, s);
    return s;
}

// ---------- prep: fp8 convert -> fb (row-major) + fbT (B-operand, LDS-image layout)
//            + per-row sumsq of QUANTIZED values (diag d_ii ~ 0 matches ref k_ii=1).
// fbT layout per 16-row group (8KB) — the exact LDS image the entropy kernel stages
// with global_load_lds (linear dest) and reads conflict-free:
//   byte = kk*2048 + half*1024 + lane*16 + w8p*8,  lane = q*16 + r
//   content = row r, K bytes [kk*128 + q*32 + (half*2+w8p)*8 .. +8)
__global__ __launch_bounds__(256) void prep_kernel(
    const float* __restrict__ feat, uint8_t* __restrict__ fb,
    uint8_t* __restrict__ fbT, float* __restrict__ sq)
{
    __shared__ __align__(16) long lt[1024];        // [chunk c 0..63][row16], swizzled
    const int t = threadIdx.x;
    const int row16 = t >> 4, seg = t & 15;
    const size_t grp = blockIdx.x;
    const size_t row = grp * 16 + row16;

    const float4* src = (const float4*)(feat + row * DIM + seg * 32);
    uint32_t wd[8];
    float s = 0.f;
#pragma unroll
    for (int i = 0; i < 4; ++i) {
        float4 a = src[2 * i], b = src[2 * i + 1];
        uint lo = (uint)__builtin_amdgcn_cvt_pk_fp8_f32(a.x, a.y, 0, false);
        lo      = (uint)__builtin_amdgcn_cvt_pk_fp8_f32(a.z, a.w, (int)lo, true);
        uint hi = (uint)__builtin_amdgcn_cvt_pk_fp8_f32(b.x, b.y, 0, false);
        hi      = (uint)__builtin_amdgcn_cvt_pk_fp8_f32(b.z, b.w, (int)hi, true);
        wd[2 * i] = lo; wd[2 * i + 1] = hi;
        s += sumsq8(lo, hi);
    }

    uint4* dst = (uint4*)(fb + row * DIM + seg * 32);
    uint4 o0; o0.x = wd[0]; o0.y = wd[1]; o0.z = wd[2]; o0.w = wd[3];
    uint4 o1; o1.x = wd[4]; o1.y = wd[5]; o1.z = wd[6]; o1.w = wd[7];
    dst[0] = o0; dst[1] = o1;

#pragma unroll
    for (int i = 0; i < 4; ++i) {
        int c = seg * 4 + i;                       // 8B chunk of this row
        long d = ((long)(unsigned)wd[2 * i + 1] << 32) | (unsigned)wd[2 * i];
        lt[c * 16 + ((row16 + c) & 15)] = d;
    }

#pragma unroll
    for (int m = 1; m < 16; m <<= 1) s += __shfl_xor(s, m);
    if (seg == 0) sq[row] = s;

    __syncthreads();
    long* ot = (long*)(fbT + grp * 8192);
#pragma unroll
    for (int i = 0; i < 4; ++i) {
        int p    = t + i * 256;                    // output long index, coalesced
        int kk   = p >> 8;                         // 128-wide K chunk
        int rem  = p & 255;
        int half = rem >> 7;                       // lo/hi 16B of the lane's 32B
        int l6   = (rem >> 1) & 63;                // dest lane
        int qq   = l6 >> 4;                        // 32-elem scale block
        int r    = l6 & 15;                        // j row in group
        int w8   = half * 2 + (p & 1);             // 8B word within lane's 32B
        int c    = kk * 16 + qq * 4 + w8;          // source 8B chunk in row
        ot[p] = lt[c * 16 + ((r + c) & 15)];
    }
}

// ---------- entropy: MX-scaled fp8 MFMA (K=128), register A + LDS ring-staged B ----
// T3+T4+T5: 4-slot LDS ring, prefetch 2 groups ahead with global_load_lds w16,
// raw s_barrier + counted s_waitcnt vmcnt(4) (stages stay in flight across
// barriers — never drained to 0 in the main loop), setprio(1) around the MFMA
// cluster. Ring distance 2 < 4 slots => stage(g+2) overwrites a slot last read
// at phase g-2, sealed by barrier(g-1): race-free.
// Occupancy is reg-capped at 2 waves/SIMD (afrag = 128 regs in the unified file),
// so the schedule — not occupancy — is the lever (m218: counted vs drain0 +38-73%).
__global__ __launch_bounds__(256, 2) void entropy_kernel(
    const uint8_t* __restrict__ fb, const uint8_t* __restrict__ fbT,
    const float* __restrict__ sq, const float* __restrict__ temp,
    float* __restrict__ Sp, float* __restrict__ Tp)
{
    __shared__ uint4 Bs[4][512];                   // 4 x 8KB ring
    __shared__ float sqlds[NG * 16];               // pj inputs, out of the vmem stream
    const int t    = threadIdx.x;
    const int w    = t >> 6;
    const int lane = t & 63;
    const int q    = lane >> 4;
    const int c16  = lane & 15;
    const int lbo  = lane * 16;

    const int flat  = blockIdx.x;
    const int combo = flat & 31;
    const int batch = combo >> 3;
    const int jh    = combo & 7;                   // == XCD id for L2 locality
    const int iblk  = flat >> 5;
    const int iw    = iblk * IPB + w * IPW;
    const size_t rowbase = (size_t)batch * N_TOK;

    const float tau    = temp[0];
    const float inv2t2 = 0.5f / (tau * tau);
    const float cg     = 1.0f / (tau * tau);

    // A fragments: 4 strips x 4 K-chunks x 32B = 128 regs, loop-invariant.
    // Issued FIRST so the counted vmcnt(4) in phase 0 retires them (FIFO).
    i32x8 afrag[4][4];
#pragma unroll
    for (int s = 0; s < 4; ++s) {
        const uint4* ap = (const uint4*)(fb + (rowbase + iw + s * 16 + c16) * DIM);
#pragma unroll
        for (int kk = 0; kk < 4; ++kk) {
            uint4 lo = ap[kk * 8 + q * 2];
            uint4 hi = ap[kk * 8 + q * 2 + 1];
            i32x8 v = {(int)lo.x, (int)lo.y, (int)lo.z, (int)lo.w,
                       (int)hi.x, (int)hi.y, (int)hi.z, (int)hi.w};
            afrag[s][kk] = v;
        }
    }
    float pi[4][4];
#pragma unroll
    for (int s = 0; s < 4; ++s)
#pragma unroll
        for (int r = 0; r < 4; ++r)
            pi[s][r] = -sq[rowbase + iw + s * 16 + q * 4 + r] * inv2t2;

    // preload the slice's sq values into LDS (512 floats = 2KB)
    {
        const float* sqslice = sq + rowbase + (size_t)jh * (N_TOK / JSPLIT);
        sqlds[t]       = sqslice[t];
        sqlds[t + 256] = sqslice[t + 256];
    }

    float S[4][4], T[4][4];
#pragma unroll
    for (int s = 0; s < 4; ++s)
#pragma unroll
        for (int r = 0; r < 4; ++r) { S[s][r] = 0.f; T[s][r] = 0.f; }

    const uint8_t* bgbase = fbT
        + ((size_t)batch * (N_TOK / 16) + (size_t)jh * NG) * 8192;

    auto stage = [&](int g) {                      // wave w copies its linear 2KB
        const uint8_t* gs = bgbase + (size_t)g * 8192 + w * 2048 + lbo;
        uint8_t* ld = (uint8_t*)(&Bs[g & 3][0]) + w * 2048;
        __builtin_amdgcn_global_load_lds((gptr_t)(const void*)gs,
                                         (lptr_t)(void*)ld, 16, 0, 0);
        __builtin_amdgcn_global_load_lds((gptr_t)(const void*)(gs + 1024),
                                         (lptr_t)(void*)(ld + 1024), 16, 0, 0);
    };
    stage(0);
    stage(1);
    // sqlds ds_writes must be visible to other waves after the first barrier
    asm volatile("s_waitcnt lgkmcnt(0)" ::: "memory");

    for (int g = 0; g < NG; ++g) {
        if (g + 2 < NG) stage(g + 2);              // keep 2 stages (4 loads) in flight
        if (g + 2 < NG)      asm volatile("s_waitcnt vmcnt(4)" ::: "memory");
        else if (g + 1 < NG) asm volatile("s_waitcnt vmcnt(2)" ::: "memory");
        else                 asm volatile("s_waitcnt vmcnt(0)" ::: "memory");
        __builtin_amdgcn_s_barrier();              // raw: no compiler drain
        __builtin_amdgcn_sched_barrier(0);         // fence: no ds_read hoist (rule 18)

        const uint8_t* bs = (const uint8_t*)(&Bs[g & 3][0]);
        float pj = -sqlds[g * 16 + c16] * inv2t2;
        f32x4 acc[4] = {{0,0,0,0},{0,0,0,0},{0,0,0,0},{0,0,0,0}};
        __builtin_amdgcn_s_setprio(1);
#pragma unroll
        for (int kk = 0; kk < 4; ++kk) {
            uint4 lo = *(const uint4*)(bs + kk * 2048 + lbo);
            uint4 hi = *(const uint4*)(bs + kk * 2048 + 1024 + lbo);
            i32x8 b = {(int)lo.x, (int)lo.y, (int)lo.z, (int)lo.w,
                       (int)hi.x, (int)hi.y, (int)hi.z, (int)hi.w};
            acc[0] = __builtin_amdgcn_mfma_scale_f32_16x16x128_f8f6f4(afrag[0][kk], b, acc[0], 0, 0, 0, 127, 0, 127);
            acc[1] = __builtin_amdgcn_mfma_scale_f32_16x16x128_f8f6f4(afrag[1][kk], b, acc[1], 0, 0, 0, 127, 0, 127);
            acc[2] = __builtin_amdgcn_mfma_scale_f32_16x16x128_f8f6f4(afrag[2][kk], b, acc[2], 0, 0, 0, 127, 0, 127);
            acc[3] = __builtin_amdgcn_mfma_scale_f32_16x16x128_f8f6f4(afrag[3][kk], b, acc[3], 0, 0, 0, 127, 0, 127);
        }
        __builtin_amdgcn_s_setprio(0);
        float m = -1e30f;
#pragma unroll
        for (int s = 0; s < 4; ++s)
#pragma unroll
            for (int r = 0; r < 4; ++r) {          // e in place of acc (dead after)
                acc[s][r] = fmaf(acc[s][r], cg, pi[s][r] + pj);
                m = fmaxf(m, acc[s][r]);
            }
        if (m > -110.0f) {                         // only diagonal-adjacent groups
#pragma unroll
            for (int s = 0; s < 4; ++s)
#pragma unroll
                for (int r = 0; r < 4; ++r) {
                    float ee = fminf(acc[s][r], 0.f);
                    float k  = __expf(ee);
                    S[s][r] += k;
                    T[s][r]  = fmaf(k, ee, T[s][r]);
                }
        }
    }

    // reduce over the 16 j-columns (c16 lanes)
#pragma unroll
    for (int m = 1; m < 16; m <<= 1)
#pragma unroll
        for (int s = 0; s < 4; ++s)
#pragma unroll
            for (int r = 0; r < 4; ++r) {
                S[s][r] += __shfl_xor(S[s][r], m);
                T[s][r] += __shfl_xor(T[s][r], m);
            }

    if (c16 == 0) {
#pragma unroll
        for (int s = 0; s < 4; ++s)
#pragma unroll
            for (int r = 0; r < 4; ++r) {
                size_t idx = (size_t)jh * BN + rowbase + iw + s * 16 + q * 4 + r;
                Sp[idx] = S[s][r];
                Tp[idx] = T[s][r];
            }
    }
}

// ---------- finalize: combine partials, entropy -> sigmoid -> scale features ----------
__global__ __launch_bounds__(256) void finalize_kernel(
    const float* __restrict__ feat, const float* __restrict__ Sp,
    const float* __restrict__ Tp, const float* __restrict__ tgt,
    const float* __restrict__ temp, float* __restrict__ out)
{
    int row  = (blockIdx.x << 2) + (threadIdx.x >> 6);   // global row 0..BN-1
    int lane = threadIdx.x & 63;
    float S = 0.0f, T = 0.0f;
#pragma unroll
    for (int j = 0; j < JSPLIT; ++j) {
        S += Sp[(size_t)j * BN + row];
        T += Tp[(size_t)j * BN + row];
    }
    float tau = temp[0];
    float E  = __logf(S) - T / S;                  // entropy (sans +1e-6, bias<4e-3)
    float cs = 1.0f / (1.0f + __expf((E - tgt[0]) / tau));

    const float4* F4 = (const float4*)(feat + (size_t)row * DIM);
    float4*       O4 = (float4*)(out + (size_t)row * DIM);
    float4 v0 = F4[lane], v1 = F4[lane + 64];
    v0.x *= cs; v0.y *= cs; v0.z *= cs; v0.w *= cs;
    v1.x *= cs; v1.y *= cs; v1.z *= cs; v1.w *= cs;
    O4[lane] = v0; O4[lane + 64] = v1;
    if (lane == 0) out[(size_t)BN * DIM + row] = cs;
}

extern "C" void kernel_launch(void* const* d_in, const int* in_sizes, int n_in,
                              void* d_out, int out_size, void* d_ws, size_t ws_size,
                              hipStream_t stream) {
    const float* feat = (const float*)d_in[0];
    const float* tgt  = (const float*)d_in[7];   // target_entropy
    const float* temp = (const float*)d_in[8];   // temperature
    float* out = (float*)d_out;

    char* ws = (char*)d_ws;
    uint8_t* fb  = (uint8_t*)ws;                               // fp8 row-major, 8.4MB
    uint8_t* fbT = fb + (size_t)BN * DIM;                      // fp8 B-layout (LDS image), 8.4MB
    float*   sq  = (float*)(fbT + (size_t)BN * DIM);           // quantized row sumsq
    float*   Sp  = sq + BN;                                    // partial S, JSPLIT slices
    float*   Tp  = Sp + (size_t)JSPLIT * BN;                   // partial T, JSPLIT slices

    prep_kernel<<<dim3(BN / 16), dim3(256), 0, stream>>>(feat, fb, fbT, sq);
    entropy_kernel<<<dim3((N_TOK / IPB) * BATCH * JSPLIT), dim3(256), 0, stream>>>(fb, fbT, sq, temp, Sp, Tp);
    finalize_kernel<<<dim3(BN / 4), dim3(256), 0, stream>>>(feat, Sp, Tp, tgt, temp, out);
}

// Round 4
// 145.239 us; speedup vs baseline: 1.0858x; 1.0216x over previous
//
#include <hip/hip_runtime.h>
#include <stdint.h>

#define N_TOK 4096
#define DIM   512
#define BATCH 4
#define BN    (BATCH * N_TOK)
#define JSPLIT 8
#define IPW   64                      // i-rows per wave (A resident in regs)
#define IPB   256                     // i-rows per block (4 waves)
#define NG    (N_TOK / JSPLIT / 16)   // 32 j-groups of 16 per slice

typedef __attribute__((ext_vector_type(4))) float f32x4;
typedef __attribute__((ext_vector_type(8))) int   i32x8;

typedef const __attribute__((address_space(1))) uint32_t* gptr_t;
typedef __attribute__((address_space(3))) uint32_t* lptr_t;

__device__ __forceinline__ float sumsq8(uint lo, uint hi) {
    float s = 0.f, f;
    f = __builtin_amdgcn_cvt_f32_fp8((int)lo, 0); s = fmaf(f, f, s);
    f = __builtin_amdgcn_cvt_f32_fp8((int)lo, 1); s = fmaf(f, f, s);
    f = __builtin_amdgcn_cvt_f32_fp8((int)lo, 2); s = fmaf(f, f, s);
    f = __builtin_amdgcn_cvt_f32_fp8((int)lo, 3); s = fmaf(f, f, s);
    f = __builtin_amdgcn_cvt_f32_fp8((int)hi, 0); s = fmaf(f, f, s);
    f = __builtin_amdgcn_cvt_f32_fp8((int)hi, 1); s = fmaf(f, f, s);
    f = __builtin_amdgcn_cvt_f32_fp8((int)hi, 2); s = fmaf(f, f, s);
    f = __builtin_amdgcn_cvt_f32_fp8((int)hi, 3); s = fmaf(f, f, s);
    return s;
}

// ---------- prep: fp8 convert -> fbT ONLY (operand-image layout; A and B per-lane
// MFMA layouts are identical for 16x16x128, so entropy reads BOTH operands from
// fbT and the old row-major fb buffer is deleted: -8.4MB stores here, -8.4MB
// loads in entropy) + per-row sumsq of QUANTIZED values.
// fbT per 16-row group (8KB):
//   byte = kk*2048 + half*1024 + lane*16 + w8p*8, lane = q*16 + r
//   content = row r, K bytes [kk*128 + q*32 + (half*2+w8p)*8 .. +8)
__global__ __launch_bounds__(256) void prep_kernel(
    const float* __restrict__ feat, uint8_t* __restrict__ fbT,
    float* __restrict__ sq)
{
    __shared__ __align__(16) long lt[1024];        // [chunk c 0..63][row16], swizzled
    const int t = threadIdx.x;
    const int row16 = t >> 4, seg = t & 15;
    const size_t grp = blockIdx.x;
    const size_t row = grp * 16 + row16;

    const float4* src = (const float4*)(feat + row * DIM + seg * 32);
    uint32_t wd[8];
    float s = 0.f;
#pragma unroll
    for (int i = 0; i < 4; ++i) {
        float4 a = src[2 * i], b = src[2 * i + 1];
        uint lo = (uint)__builtin_amdgcn_cvt_pk_fp8_f32(a.x, a.y, 0, false);
        lo      = (uint)__builtin_amdgcn_cvt_pk_fp8_f32(a.z, a.w, (int)lo, true);
        uint hi = (uint)__builtin_amdgcn_cvt_pk_fp8_f32(b.x, b.y, 0, false);
        hi      = (uint)__builtin_amdgcn_cvt_pk_fp8_f32(b.z, b.w, (int)hi, true);
        wd[2 * i] = lo; wd[2 * i + 1] = hi;
        s += sumsq8(lo, hi);
    }

#pragma unroll
    for (int i = 0; i < 4; ++i) {
        int c = seg * 4 + i;                       // 8B chunk of this row
        long d = ((long)(unsigned)wd[2 * i + 1] << 32) | (unsigned)wd[2 * i];
        lt[c * 16 + ((row16 + c) & 15)] = d;
    }

#pragma unroll
    for (int m = 1; m < 16; m <<= 1) s += __shfl_xor(s, m);
    if (seg == 0) sq[row] = s;

    __syncthreads();
    long* ot = (long*)(fbT + grp * 8192);
#pragma unroll
    for (int i = 0; i < 4; ++i) {
        int p    = t + i * 256;                    // output long index, coalesced
        int kk   = p >> 8;                         // 128-wide K chunk
        int rem  = p & 255;
        int half = rem >> 7;                       // lo/hi 16B of the lane's 32B
        int l6   = (rem >> 1) & 63;                // dest lane
        int qq   = l6 >> 4;                        // 32-elem scale block
        int r    = l6 & 15;                        // j row in group
        int w8   = half * 2 + (p & 1);             // 8B word within lane's 32B
        int c    = kk * 16 + qq * 4 + w8;          // source 8B chunk in row
        ot[p] = lt[c * 16 + ((r + c) & 15)];
    }
}

// ---------- entropy: MX-scaled fp8 MFMA (K=128), register A + PRIVATE per-wave
// LDS ring for B. NO barriers in the main loop: each wave owns a 2-slot (2x8KB)
// ring and stages its own full group via 8x global_load_lds(16B). Sync is purely
// the wave's own counted vmcnt: prologue 16 outstanding; each phase vmcnt(8)
// retires group g; stage(g+2) restores 16; last phase drains vmcnt(0).
// Overwrite hazard (stage(g+2) targets the slot read THIS phase) is fenced by
// lgkmcnt(0)+sched_barrier(0) after the final ds_read, before the stage.
// Cost: 4x B reads (2MB/CU, L2-resident slice, ~80GB/s/CU << 135 ceiling);
// benefit: zero barrier stall, waves free-run (m233: barrier drain was ~70%).
__global__ __launch_bounds__(256, 2) void entropy_kernel(
    const uint8_t* __restrict__ fbT,
    const float* __restrict__ sq, const float* __restrict__ temp,
    float* __restrict__ Sp, float* __restrict__ Tp)
{
    __shared__ uint4 ring[4][2][512];              // [wave][slot][8KB] private rings
    __shared__ float sqlds[NG * 16];               // pj inputs, off the vmem stream
    const int t    = threadIdx.x;
    const int w    = t >> 6;
    const int lane = t & 63;
    const int q    = lane >> 4;
    const int c16  = lane & 15;
    const int lbo  = lane * 16;

    const int flat  = blockIdx.x;
    const int combo = flat & 31;
    const int batch = combo >> 3;
    const int jh    = combo & 7;                   // == XCD id for L2 locality
    const int iblk  = flat >> 5;
    const int iw    = iblk * IPB + w * IPW;
    const size_t rowbase = (size_t)batch * N_TOK;

    const float tau    = temp[0];
    const float inv2t2 = 0.5f / (tau * tau);
    const float cg_    = 1.0f / (tau * tau);

    // A fragments from fbT (A/B per-lane layouts identical for 16x16x128):
    // strip s lives in fbT group (rowbase+iw)/16 + s; lane's 32B = two uint4 at
    // kk*2048 + {0,1024} + lane*16. Coalesced 1KB per instruction.
    i32x8 afrag[4][4];
#pragma unroll
    for (int s = 0; s < 4; ++s) {
        const uint8_t* ga = fbT + ((rowbase + iw) / 16 + s) * 8192;
#pragma unroll
        for (int kk = 0; kk < 4; ++kk) {
            uint4 lo = *(const uint4*)(ga + kk * 2048 + lbo);
            uint4 hi = *(const uint4*)(ga + kk * 2048 + 1024 + lbo);
            i32x8 v = {(int)lo.x, (int)lo.y, (int)lo.z, (int)lo.w,
                       (int)hi.x, (int)hi.y, (int)hi.z, (int)hi.w};
            afrag[s][kk] = v;
        }
    }
    float pi_[4][4];
    float pim = -1e30f;                            // max_i pi, for the early-out
#pragma unroll
    for (int s = 0; s < 4; ++s) {
        float4 p4 = *(const float4*)(sq + rowbase + iw + s * 16 + q * 4);
        pi_[s][0] = -p4.x * inv2t2; pi_[s][1] = -p4.y * inv2t2;
        pi_[s][2] = -p4.z * inv2t2; pi_[s][3] = -p4.w * inv2t2;
        pim = fmaxf(pim, fmaxf(fmaxf(pi_[s][0], pi_[s][1]),
                               fmaxf(pi_[s][2], pi_[s][3])));
    }
    {   // preload the slice's sq values into LDS (512 floats = 2KB)
        const float* sqslice = sq + rowbase + (size_t)jh * (N_TOK / JSPLIT);
        sqlds[t]       = sqslice[t];
        sqlds[t + 256] = sqslice[t + 256];
    }

    float S[4][4], T[4][4];
#pragma unroll
    for (int s = 0; s < 4; ++s)
#pragma unroll
        for (int r = 0; r < 4; ++r) { S[s][r] = 0.f; T[s][r] = 0.f; }

    const uint8_t* bgbase = fbT
        + ((size_t)batch * (N_TOK / 16) + (size_t)jh * NG) * 8192;

    auto stage = [&](int g, int slot) {            // wave stages its OWN full 8KB
        const uint8_t* gs = bgbase + (size_t)g * 8192 + lbo;
        uint8_t* ld = (uint8_t*)(&ring[w][slot][0]);
#pragma unroll
        for (int i = 0; i < 8; ++i)
            __builtin_amdgcn_global_load_lds(
                (gptr_t)(const void*)(gs + i * 1024),
                (lptr_t)(void*)(ld + i * 1024), 16, 0, 0);
    };

    stage(0, 0);
    stage(1, 1);
    // one-time barrier: sqlds writes visible; raw (no vmcnt drain) keeps the
    // counted-vmcnt ledger intact (16 outstanding entering the loop).
    asm volatile("s_waitcnt lgkmcnt(0)" ::: "memory");
    __builtin_amdgcn_s_barrier();

    for (int g = 0; g < NG; ++g) {
        if (g < NG - 1) asm volatile("s_waitcnt vmcnt(8)" ::: "memory");
        else            asm volatile("s_waitcnt vmcnt(0)" ::: "memory");
        __builtin_amdgcn_sched_barrier(0);         // no ds_read hoist (rule 18)

        const uint8_t* bs = (const uint8_t*)(&ring[w][g & 1][0]);
        float pj = -sqlds[g * 16 + c16] * inv2t2;
        f32x4 acc[4] = {{0,0,0,0},{0,0,0,0},{0,0,0,0},{0,0,0,0}};
        __builtin_amdgcn_s_setprio(1);
#pragma unroll
        for (int kk = 0; kk < 4; kk += 2) {        // 2 B chunks in flight (32 regs)
            uint4 l0 = *(const uint4*)(bs + kk * 2048 + lbo);
            uint4 h0 = *(const uint4*)(bs + kk * 2048 + 1024 + lbo);
            uint4 l1 = *(const uint4*)(bs + (kk + 1) * 2048 + lbo);
            uint4 h1 = *(const uint4*)(bs + (kk + 1) * 2048 + 1024 + lbo);
            i32x8 b0 = {(int)l0.x, (int)l0.y, (int)l0.z, (int)l0.w,
                        (int)h0.x, (int)h0.y, (int)h0.z, (int)h0.w};
            i32x8 b1 = {(int)l1.x, (int)l1.y, (int)l1.z, (int)l1.w,
                        (int)h1.x, (int)h1.y, (int)h1.z, (int)h1.w};
            acc[0] = __builtin_amdgcn_mfma_scale_f32_16x16x128_f8f6f4(afrag[0][kk], b0, acc[0], 0, 0, 0, 127, 0, 127);
            acc[1] = __builtin_amdgcn_mfma_scale_f32_16x16x128_f8f6f4(afrag[1][kk], b0, acc[1], 0, 0, 0, 127, 0, 127);
            acc[2] = __builtin_amdgcn_mfma_scale_f32_16x16x128_f8f6f4(afrag[2][kk], b0, acc[2], 0, 0, 0, 127, 0, 127);
            acc[3] = __builtin_amdgcn_mfma_scale_f32_16x16x128_f8f6f4(afrag[3][kk], b0, acc[3], 0, 0, 0, 127, 0, 127);
            acc[0] = __builtin_amdgcn_mfma_scale_f32_16x16x128_f8f6f4(afrag[0][kk+1], b1, acc[0], 0, 0, 0, 127, 0, 127);
            acc[1] = __builtin_amdgcn_mfma_scale_f32_16x16x128_f8f6f4(afrag[1][kk+1], b1, acc[1], 0, 0, 0, 127, 0, 127);
            acc[2] = __builtin_amdgcn_mfma_scale_f32_16x16x128_f8f6f4(afrag[2][kk+1], b1, acc[2], 0, 0, 0, 127, 0, 127);
            acc[3] = __builtin_amdgcn_mfma_scale_f32_16x16x128_f8f6f4(afrag[3][kk+1], b1, acc[3], 0, 0, 0, 127, 0, 127);
        }
        __builtin_amdgcn_s_setprio(0);

        // all ds_reads of this slot retired -> safe to DMA-overwrite it with g+2
        asm volatile("s_waitcnt lgkmcnt(0)" ::: "memory");
        __builtin_amdgcn_sched_barrier(0);
        if (g + 2 < NG) stage(g + 2, g & 1);

        // early-out: bound >= true per-lane max of e; extra-taken groups add
        // exp(<=-110) == 0.0f exactly -> bit-identical to the full path.
        float m0 = fmaxf(fmaxf(acc[0][0], acc[0][1]), fmaxf(acc[0][2], acc[0][3]));
        float m1 = fmaxf(fmaxf(acc[1][0], acc[1][1]), fmaxf(acc[1][2], acc[1][3]));
        float m2 = fmaxf(fmaxf(acc[2][0], acc[2][1]), fmaxf(acc[2][2], acc[2][3]));
        float m3 = fmaxf(fmaxf(acc[3][0], acc[3][1]), fmaxf(acc[3][2], acc[3][3]));
        float mm = fmaxf(fmaxf(m0, m1), fmaxf(m2, m3));
        float bound = fmaf(mm, cg_, pim + pj);
        if (bound > -110.0f) {
#pragma unroll
            for (int s = 0; s < 4; ++s)
#pragma unroll
                for (int r = 0; r < 4; ++r) {
                    float e  = fmaf(acc[s][r], cg_, pi_[s][r] + pj);
                    float ee = fminf(e, 0.f);
                    float k  = __expf(ee);
                    S[s][r] += k;
                    T[s][r]  = fmaf(k, ee, T[s][r]);
                }
        }
    }

    // reduce over the 16 j-columns (c16 lanes)
#pragma unroll
    for (int m = 1; m < 16; m <<= 1)
#pragma unroll
        for (int s = 0; s < 4; ++s)
#pragma unroll
            for (int r = 0; r < 4; ++r) {
                S[s][r] += __shfl_xor(S[s][r], m);
                T[s][r] += __shfl_xor(T[s][r], m);
            }

    if (c16 == 0) {
#pragma unroll
        for (int s = 0; s < 4; ++s)
#pragma unroll
            for (int r = 0; r < 4; ++r) {
                size_t idx = (size_t)jh * BN + rowbase + iw + s * 16 + q * 4 + r;
                Sp[idx] = S[s][r];
                Tp[idx] = T[s][r];
            }
    }
}

// ---------- finalize: combine partials, entropy -> sigmoid -> scale features ----------
__global__ __launch_bounds__(256) void finalize_kernel(
    const float* __restrict__ feat, const float* __restrict__ Sp,
    const float* __restrict__ Tp, const float* __restrict__ tgt,
    const float* __restrict__ temp, float* __restrict__ out)
{
    int row  = (blockIdx.x << 2) + (threadIdx.x >> 6);   // global row 0..BN-1
    int lane = threadIdx.x & 63;
    float S = 0.0f, T = 0.0f;
#pragma unroll
    for (int j = 0; j < JSPLIT; ++j) {
        S += Sp[(size_t)j * BN + row];
        T += Tp[(size_t)j * BN + row];
    }
    float tau = temp[0];
    float E  = __logf(S) - T / S;                  // entropy (sans +1e-6, bias<4e-3)
    float cs = 1.0f / (1.0f + __expf((E - tgt[0]) / tau));

    const float4* F4 = (const float4*)(feat + (size_t)row * DIM);
    float4*       O4 = (float4*)(out + (size_t)row * DIM);
    float4 v0 = F4[lane], v1 = F4[lane + 64];
    v0.x *= cs; v0.y *= cs; v0.z *= cs; v0.w *= cs;
    v1.x *= cs; v1.y *= cs; v1.z *= cs; v1.w *= cs;
    O4[lane] = v0; O4[lane + 64] = v1;
    if (lane == 0) out[(size_t)BN * DIM + row] = cs;
}

extern "C" void kernel_launch(void* const* d_in, const int* in_sizes, int n_in,
                              void* d_out, int out_size, void* d_ws, size_t ws_size,
                              hipStream_t stream) {
    const float* feat = (const float*)d_in[0];
    const float* tgt  = (const float*)d_in[7];   // target_entropy
    const float* temp = (const float*)d_in[8];   // temperature
    float* out = (float*)d_out;

    char* ws = (char*)d_ws;
    uint8_t* fbT = (uint8_t*)ws;                               // fp8 operand-image, 8.4MB
    float*   sq  = (float*)(fbT + (size_t)BN * DIM);           // quantized row sumsq
    float*   Sp  = sq + BN;                                    // partial S, JSPLIT slices
    float*   Tp  = Sp + (size_t)JSPLIT * BN;                   // partial T, JSPLIT slices

    prep_kernel<<<dim3(BN / 16), dim3(256), 0, stream>>>(feat, fbT, sq);
    entropy_kernel<<<dim3((N_TOK / IPB) * BATCH * JSPLIT), dim3(256), 0, stream>>>(fbT, sq, temp, Sp, Tp);
    finalize_kernel<<<dim3(BN / 4), dim3(256), 0, stream>>>(feat, Sp, Tp, tgt, temp, out);
}

// Round 5
// 143.890 us; speedup vs baseline: 1.0960x; 1.0094x over previous
//
#include <hip/hip_runtime.h>
#include <stdint.h>

#define N_TOK 4096
#define DIM   512
#define BATCH 4
#define BN    (BATCH * N_TOK)
#define JSPLIT 8
#define IPW   64                      // i-rows per wave (A resident in regs)
#define IPB   256                     // i-rows per block (4 waves)
#define NG    (N_TOK / JSPLIT / 16)   // 32 j-groups of 16 per slice
#define SPG   4                       // j-groups per superphase (un-fenced body)
#define NSP   (NG / SPG)              // 8 superphases

typedef __attribute__((ext_vector_type(4))) float f32x4;
typedef __attribute__((ext_vector_type(8))) int   i32x8;

typedef const __attribute__((address_space(1))) uint32_t* gptr_t;
typedef __attribute__((address_space(3))) uint32_t* lptr_t;

__device__ __forceinline__ float sumsq8(uint lo, uint hi) {
    float s = 0.f, f;
    f = __builtin_amdgcn_cvt_f32_fp8((int)lo, 0); s = fmaf(f, f, s);
    f = __builtin_amdgcn_cvt_f32_fp8((int)lo, 1); s = fmaf(f, f, s);
    f = __builtin_amdgcn_cvt_f32_fp8((int)lo, 2); s = fmaf(f, f, s);
    f = __builtin_amdgcn_cvt_f32_fp8((int)lo, 3); s = fmaf(f, f, s);
    f = __builtin_amdgcn_cvt_f32_fp8((int)hi, 0); s = fmaf(f, f, s);
    f = __builtin_amdgcn_cvt_f32_fp8((int)hi, 1); s = fmaf(f, f, s);
    f = __builtin_amdgcn_cvt_f32_fp8((int)hi, 2); s = fmaf(f, f, s);
    f = __builtin_amdgcn_cvt_f32_fp8((int)hi, 3); s = fmaf(f, f, s);
    return s;
}

// ---------- prep: fp8 convert -> fbT (operand-image layout; A and B per-lane MFMA
// layouts are identical for 16x16x128, so entropy reads BOTH operands from fbT)
// + per-row sumsq of QUANTIZED values (diag d_ii ~ 0 matches ref k_ii=1).
// fbT per 16-row group (8KB):
//   byte = kk*2048 + half*1024 + lane*16 + w8p*8, lane = q*16 + r
//   content = row r, K bytes [kk*128 + q*32 + (half*2+w8p)*8 .. +8)
__global__ __launch_bounds__(256) void prep_kernel(
    const float* __restrict__ feat, uint8_t* __restrict__ fbT,
    float* __restrict__ sq)
{
    __shared__ __align__(16) long lt[1024];        // [chunk c 0..63][row16], swizzled
    const int t = threadIdx.x;
    const int row16 = t >> 4, seg = t & 15;
    const size_t grp = blockIdx.x;
    const size_t row = grp * 16 + row16;

    const float4* src = (const float4*)(feat + row * DIM + seg * 32);
    uint32_t wd[8];
    float s = 0.f;
#pragma unroll
    for (int i = 0; i < 4; ++i) {
        float4 a = src[2 * i], b = src[2 * i + 1];
        uint lo = (uint)__builtin_amdgcn_cvt_pk_fp8_f32(a.x, a.y, 0, false);
        lo      = (uint)__builtin_amdgcn_cvt_pk_fp8_f32(a.z, a.w, (int)lo, true);
        uint hi = (uint)__builtin_amdgcn_cvt_pk_fp8_f32(b.x, b.y, 0, false);
        hi      = (uint)__builtin_amdgcn_cvt_pk_fp8_f32(b.z, b.w, (int)hi, true);
        wd[2 * i] = lo; wd[2 * i + 1] = hi;
        s += sumsq8(lo, hi);
    }

#pragma unroll
    for (int i = 0; i < 4; ++i) {
        int c = seg * 4 + i;                       // 8B chunk of this row
        long d = ((long)(unsigned)wd[2 * i + 1] << 32) | (unsigned)wd[2 * i];
        lt[c * 16 + ((row16 + c) & 15)] = d;
    }

#pragma unroll
    for (int m = 1; m < 16; m <<= 1) s += __shfl_xor(s, m);
    if (seg == 0) sq[row] = s;

    __syncthreads();
    long* ot = (long*)(fbT + grp * 8192);
#pragma unroll
    for (int i = 0; i < 4; ++i) {
        int p    = t + i * 256;                    // output long index, coalesced
        int kk   = p >> 8;                         // 128-wide K chunk
        int rem  = p & 255;
        int half = rem >> 7;                       // lo/hi 16B of the lane's 32B
        int l6   = (rem >> 1) & 63;                // dest lane
        int qq   = l6 >> 4;                        // 32-elem scale block
        int r    = l6 & 15;                        // j row in group
        int w8   = half * 2 + (p & 1);             // 8B word within lane's 32B
        int c    = kk * 16 + qq * 4 + w8;          // source 8B chunk in row
        ot[p] = lt[c * 16 + ((r + c) & 15)];
    }
}

// ---------- entropy: MX-scaled fp8 MFMA (K=128), register A + block-shared
// double-buffered B, SUPERPHASE schedule: 4 j-groups per sync with ZERO fences
// inside the body. Rationale (R2 vs R4 post-mortem): per-group fences forced
// in-wave serialization [ds_read latency -> 4-deep MFMA chains -> VALU tail]
// ~1100+ cyc/group; shared staging is 1x L2 traffic (16KB/CU/group vs R4's 64KB).
// Per superphase: vmcnt(8)+barrier (P_sp resident: own loads oldest-8, barrier
// confirms all waves), 4 un-fenced groups (32 ds_read / 64 MFMA / 4 tails —
// compiler pipelines freely), lgkmcnt(0)+barrier (reads sealed), stage P_{sp+2}
// into buf[sp&1] (safe: just-confirmed drained). Ledger: prologue 16 out; each
// phase vmcnt(8) retires its 8; last phase vmcnt(0).
__global__ __launch_bounds__(256, 2) void entropy_kernel(
    const uint8_t* __restrict__ fbT,
    const float* __restrict__ sq, const float* __restrict__ temp,
    float* __restrict__ Sp, float* __restrict__ Tp)
{
    __shared__ uint4 buf[2][2048];                 // 2 x 32KB (4 groups x 8KB each)
    __shared__ float sqlds[NG * 16];               // pj inputs, off the vmem stream
    const int t    = threadIdx.x;
    const int w    = t >> 6;
    const int lane = t & 63;
    const int q    = lane >> 4;
    const int c16  = lane & 15;
    const int lbo  = lane * 16;

    const int flat  = blockIdx.x;
    const int combo = flat & 31;
    const int batch = combo >> 3;
    const int jh    = combo & 7;                   // == XCD id for L2 locality
    const int iblk  = flat >> 5;
    const int iw    = iblk * IPB + w * IPW;
    const size_t rowbase = (size_t)batch * N_TOK;

    const float tau    = temp[0];
    const float inv2t2 = 0.5f / (tau * tau);
    const float cg_    = 1.0f / (tau * tau);

    // A fragments from fbT (A/B per-lane layouts identical for 16x16x128)
    i32x8 afrag[4][4];
#pragma unroll
    for (int s = 0; s < 4; ++s) {
        const uint8_t* ga = fbT + ((rowbase + iw) / 16 + s) * 8192;
#pragma unroll
        for (int kk = 0; kk < 4; ++kk) {
            uint4 lo = *(const uint4*)(ga + kk * 2048 + lbo);
            uint4 hi = *(const uint4*)(ga + kk * 2048 + 1024 + lbo);
            i32x8 v = {(int)lo.x, (int)lo.y, (int)lo.z, (int)lo.w,
                       (int)hi.x, (int)hi.y, (int)hi.z, (int)hi.w};
            afrag[s][kk] = v;
        }
    }
    float pi_[4][4];
    float pim = -1e30f;                            // max_i pi, for the early-out
#pragma unroll
    for (int s = 0; s < 4; ++s) {
        float4 p4 = *(const float4*)(sq + rowbase + iw + s * 16 + q * 4);
        pi_[s][0] = -p4.x * inv2t2; pi_[s][1] = -p4.y * inv2t2;
        pi_[s][2] = -p4.z * inv2t2; pi_[s][3] = -p4.w * inv2t2;
        pim = fmaxf(pim, fmaxf(fmaxf(pi_[s][0], pi_[s][1]),
                               fmaxf(pi_[s][2], pi_[s][3])));
    }
    {   // preload the slice's sq values into LDS (512 floats = 2KB)
        const float* sqslice = sq + rowbase + (size_t)jh * (N_TOK / JSPLIT);
        sqlds[t]       = sqslice[t];
        sqlds[t + 256] = sqslice[t + 256];
    }

    float S[4][4], T[4][4];
#pragma unroll
    for (int s = 0; s < 4; ++s)
#pragma unroll
        for (int r = 0; r < 4; ++r) { S[s][r] = 0.f; T[s][r] = 0.f; }

    const uint8_t* bgbase = fbT
        + ((size_t)batch * (N_TOK / 16) + (size_t)jh * NG) * 8192;

    auto stage_sp = [&](int sp, int b) {           // wave w: its 2KB of each group
#pragma unroll
        for (int i = 0; i < SPG; ++i) {
            const uint8_t* gs = bgbase + ((size_t)sp * SPG + i) * 8192 + w * 2048 + lbo;
            uint8_t* ld = (uint8_t*)(&buf[b][0]) + i * 8192 + w * 2048;
            __builtin_amdgcn_global_load_lds((gptr_t)(const void*)gs,
                                             (lptr_t)(void*)ld, 16, 0, 0);
            __builtin_amdgcn_global_load_lds((gptr_t)(const void*)(gs + 1024),
                                             (lptr_t)(void*)(ld + 1024), 16, 0, 0);
        }
    };

    stage_sp(0, 0);
    stage_sp(1, 1);
    // one-time: sqlds visible to all waves (raw barrier keeps vmcnt ledger intact)
    asm volatile("s_waitcnt lgkmcnt(0)" ::: "memory");
    __builtin_amdgcn_s_barrier();

    for (int sp = 0; sp < NSP; ++sp) {
        if (sp < NSP - 1) asm volatile("s_waitcnt vmcnt(8)" ::: "memory");
        else              asm volatile("s_waitcnt vmcnt(0)" ::: "memory");
        __builtin_amdgcn_s_barrier();              // all waves' stage(sp) confirmed
        __builtin_amdgcn_sched_barrier(0);

        const uint8_t* sb = (const uint8_t*)(&buf[sp & 1][0]);
        __builtin_amdgcn_s_setprio(1);
#pragma unroll
        for (int i = 0; i < SPG; ++i) {            // UN-FENCED 4-group body
            const int g = sp * SPG + i;
            const uint8_t* bs = sb + i * 8192;
            float pj = -sqlds[g * 16 + c16] * inv2t2;
            f32x4 acc[4] = {{0,0,0,0},{0,0,0,0},{0,0,0,0},{0,0,0,0}};
#pragma unroll
            for (int kk = 0; kk < 4; ++kk) {
                uint4 lo = *(const uint4*)(bs + kk * 2048 + lbo);
                uint4 hi = *(const uint4*)(bs + kk * 2048 + 1024 + lbo);
                i32x8 b = {(int)lo.x, (int)lo.y, (int)lo.z, (int)lo.w,
                           (int)hi.x, (int)hi.y, (int)hi.z, (int)hi.w};
                acc[0] = __builtin_amdgcn_mfma_scale_f32_16x16x128_f8f6f4(afrag[0][kk], b, acc[0], 0, 0, 0, 127, 0, 127);
                acc[1] = __builtin_amdgcn_mfma_scale_f32_16x16x128_f8f6f4(afrag[1][kk], b, acc[1], 0, 0, 0, 127, 0, 127);
                acc[2] = __builtin_amdgcn_mfma_scale_f32_16x16x128_f8f6f4(afrag[2][kk], b, acc[2], 0, 0, 0, 127, 0, 127);
                acc[3] = __builtin_amdgcn_mfma_scale_f32_16x16x128_f8f6f4(afrag[3][kk], b, acc[3], 0, 0, 0, 127, 0, 127);
            }
            // early-out: bound >= true per-lane max of e; extra-taken groups add
            // exp(<=-110) == 0.0f exactly -> bit-identical to the full path.
            float m0 = fmaxf(fmaxf(acc[0][0], acc[0][1]), fmaxf(acc[0][2], acc[0][3]));
            float m1 = fmaxf(fmaxf(acc[1][0], acc[1][1]), fmaxf(acc[1][2], acc[1][3]));
            float m2 = fmaxf(fmaxf(acc[2][0], acc[2][1]), fmaxf(acc[2][2], acc[2][3]));
            float m3 = fmaxf(fmaxf(acc[3][0], acc[3][1]), fmaxf(acc[3][2], acc[3][3]));
            float mm = fmaxf(fmaxf(m0, m1), fmaxf(m2, m3));
            float bound = fmaf(mm, cg_, pim + pj);
            if (bound > -110.0f) {
#pragma unroll
                for (int s = 0; s < 4; ++s)
#pragma unroll
                    for (int r = 0; r < 4; ++r) {
                        float e  = fmaf(acc[s][r], cg_, pi_[s][r] + pj);
                        float ee = fminf(e, 0.f);
                        float k  = __expf(ee);
                        S[s][r] += k;
                        T[s][r]  = fmaf(k, ee, T[s][r]);
                    }
            }
        }
        __builtin_amdgcn_s_setprio(0);

        // seal own ds_reads of buf[sp&1]; barrier -> ALL waves sealed -> safe to
        // DMA-overwrite with superphase sp+2.
        asm volatile("s_waitcnt lgkmcnt(0)" ::: "memory");
        __builtin_amdgcn_s_barrier();
        __builtin_amdgcn_sched_barrier(0);
        if (sp + 2 < NSP) stage_sp(sp + 2, sp & 1);
    }

    // reduce over the 16 j-columns (c16 lanes)
#pragma unroll
    for (int m = 1; m < 16; m <<= 1)
#pragma unroll
        for (int s = 0; s < 4; ++s)
#pragma unroll
            for (int r = 0; r < 4; ++r) {
                S[s][r] += __shfl_xor(S[s][r], m);
                T[s][r] += __shfl_xor(T[s][r], m);
            }

    if (c16 == 0) {
#pragma unroll
        for (int s = 0; s < 4; ++s)
#pragma unroll
            for (int r = 0; r < 4; ++r) {
                size_t idx = (size_t)jh * BN + rowbase + iw + s * 16 + q * 4 + r;
                Sp[idx] = S[s][r];
                Tp[idx] = T[s][r];
            }
    }
}

// ---------- finalize: combine partials, entropy -> sigmoid -> scale features ----------
__global__ __launch_bounds__(256) void finalize_kernel(
    const float* __restrict__ feat, const float* __restrict__ Sp,
    const float* __restrict__ Tp, const float* __restrict__ tgt,
    const float* __restrict__ temp, float* __restrict__ out)
{
    int row  = (blockIdx.x << 2) + (threadIdx.x >> 6);   // global row 0..BN-1
    int lane = threadIdx.x & 63;
    float S = 0.0f, T = 0.0f;
#pragma unroll
    for (int j = 0; j < JSPLIT; ++j) {
        S += Sp[(size_t)j * BN + row];
        T += Tp[(size_t)j * BN + row];
    }
    float tau = temp[0];
    float E  = __logf(S) - T / S;                  // entropy (sans +1e-6, bias<4e-3)
    float cs = 1.0f / (1.0f + __expf((E - tgt[0]) / tau));

    const float4* F4 = (const float4*)(feat + (size_t)row * DIM);
    float4*       O4 = (float4*)(out + (size_t)row * DIM);
    float4 v0 = F4[lane], v1 = F4[lane + 64];
    v0.x *= cs; v0.y *= cs; v0.z *= cs; v0.w *= cs;
    v1.x *= cs; v1.y *= cs; v1.z *= cs; v1.w *= cs;
    O4[lane] = v0; O4[lane + 64] = v1;
    if (lane == 0) out[(size_t)BN * DIM + row] = cs;
}

extern "C" void kernel_launch(void* const* d_in, const int* in_sizes, int n_in,
                              void* d_out, int out_size, void* d_ws, size_t ws_size,
                              hipStream_t stream) {
    const float* feat = (const float*)d_in[0];
    const float* tgt  = (const float*)d_in[7];   // target_entropy
    const float* temp = (const float*)d_in[8];   // temperature
    float* out = (float*)d_out;

    char* ws = (char*)d_ws;
    uint8_t* fbT = (uint8_t*)ws;                               // fp8 operand-image, 8.4MB
    float*   sq  = (float*)(fbT + (size_t)BN * DIM);           // quantized row sumsq
    float*   Sp  = sq + BN;                                    // partial S, JSPLIT slices
    float*   Tp  = Sp + (size_t)JSPLIT * BN;                   // partial T, JSPLIT slices

    prep_kernel<<<dim3(BN / 16), dim3(256), 0, stream>>>(feat, fbT, sq);
    entropy_kernel<<<dim3((N_TOK / IPB) * BATCH * JSPLIT), dim3(256), 0, stream>>>(fbT, sq, temp, Sp, Tp);
    finalize_kernel<<<dim3(BN / 4), dim3(256), 0, stream>>>(feat, Sp, Tp, tgt, temp, out);
}

// Round 6
// 142.063 us; speedup vs baseline: 1.1100x; 1.0129x over previous
//
#include <hip/hip_runtime.h>
#include <stdint.h>

#define N_TOK 4096
#define DIM   512
#define BATCH 4
#define BN    (BATCH * N_TOK)
#define JSPLIT 8
#define IPW   32                      // i-rows per wave (A resident: 64 regs)
#define IPB   128                     // i-rows per block (4 waves)
#define NG    (N_TOK / JSPLIT / 16)   // 32 j-groups of 16 per slice
#define SPG   2                       // j-groups per superphase (un-fenced body)
#define NSP   (NG / SPG)              // 16 superphases

typedef __attribute__((ext_vector_type(4))) float f32x4;
typedef __attribute__((ext_vector_type(8))) int   i32x8;

typedef const __attribute__((address_space(1))) uint32_t* gptr_t;
typedef __attribute__((address_space(3))) uint32_t* lptr_t;

__device__ __forceinline__ float sumsq8(uint lo, uint hi) {
    float s = 0.f, f;
    f = __builtin_amdgcn_cvt_f32_fp8((int)lo, 0); s = fmaf(f, f, s);
    f = __builtin_amdgcn_cvt_f32_fp8((int)lo, 1); s = fmaf(f, f, s);
    f = __builtin_amdgcn_cvt_f32_fp8((int)lo, 2); s = fmaf(f, f, s);
    f = __builtin_amdgcn_cvt_f32_fp8((int)lo, 3); s = fmaf(f, f, s);
    f = __builtin_amdgcn_cvt_f32_fp8((int)hi, 0); s = fmaf(f, f, s);
    f = __builtin_amdgcn_cvt_f32_fp8((int)hi, 1); s = fmaf(f, f, s);
    f = __builtin_amdgcn_cvt_f32_fp8((int)hi, 2); s = fmaf(f, f, s);
    f = __builtin_amdgcn_cvt_f32_fp8((int)hi, 3); s = fmaf(f, f, s);
    return s;
}

// ---------- prep: fp8 convert -> fbT (operand-image layout; A and B per-lane MFMA
// layouts are identical for 16x16x128, so entropy reads BOTH operands from fbT)
// + per-row sumsq of QUANTIZED values (diag d_ii ~ 0 matches ref k_ii=1).
// fbT per 16-row group (8KB):
//   byte = kk*2048 + half*1024 + lane*16 + w8p*8, lane = q*16 + r
//   content = row r, K bytes [kk*128 + q*32 + (half*2+w8p)*8 .. +8)
__global__ __launch_bounds__(256) void prep_kernel(
    const float* __restrict__ feat, uint8_t* __restrict__ fbT,
    float* __restrict__ sq)
{
    __shared__ __align__(16) long lt[1024];        // [chunk c 0..63][row16], swizzled
    const int t = threadIdx.x;
    const int row16 = t >> 4, seg = t & 15;
    const size_t grp = blockIdx.x;
    const size_t row = grp * 16 + row16;

    const float4* src = (const float4*)(feat + row * DIM + seg * 32);
    uint32_t wd[8];
    float s = 0.f;
#pragma unroll
    for (int i = 0; i < 4; ++i) {
        float4 a = src[2 * i], b = src[2 * i + 1];
        uint lo = (uint)__builtin_amdgcn_cvt_pk_fp8_f32(a.x, a.y, 0, false);
        lo      = (uint)__builtin_amdgcn_cvt_pk_fp8_f32(a.z, a.w, (int)lo, true);
        uint hi = (uint)__builtin_amdgcn_cvt_pk_fp8_f32(b.x, b.y, 0, false);
        hi      = (uint)__builtin_amdgcn_cvt_pk_fp8_f32(b.z, b.w, (int)hi, true);
        wd[2 * i] = lo; wd[2 * i + 1] = hi;
        s += sumsq8(lo, hi);
    }

#pragma unroll
    for (int i = 0; i < 4; ++i) {
        int c = seg * 4 + i;                       // 8B chunk of this row
        long d = ((long)(unsigned)wd[2 * i + 1] << 32) | (unsigned)wd[2 * i];
        lt[c * 16 + ((row16 + c) & 15)] = d;
    }

#pragma unroll
    for (int m = 1; m < 16; m <<= 1) s += __shfl_xor(s, m);
    if (seg == 0) sq[row] = s;

    __syncthreads();
    long* ot = (long*)(fbT + grp * 8192);
#pragma unroll
    for (int i = 0; i < 4; ++i) {
        int p    = t + i * 256;                    // output long index, coalesced
        int kk   = p >> 8;                         // 128-wide K chunk
        int rem  = p & 255;
        int half = rem >> 7;                       // lo/hi 16B of the lane's 32B
        int l6   = (rem >> 1) & 63;                // dest lane
        int qq   = l6 >> 4;                        // 32-elem scale block
        int r    = l6 & 15;                        // j row in group
        int w8   = half * 2 + (p & 1);             // 8B word within lane's 32B
        int c    = kk * 16 + qq * 4 + w8;          // source 8B chunk in row
        ot[p] = lt[c * 16 + ((r + c) & 15)];
    }
}

// ---------- entropy: MX-scaled fp8 MFMA (K=128), register A + block-shared
// double-buffered B, superphase schedule (2 groups per sync, un-fenced body).
// OCCUPANCY DOUBLING (R5 post-mortem: 3 schedules all ~3200cyc/group at
// 2 waves/SIMD => per-wave stream is the limit, only more waves can cover it):
// IPW 64->32 halves A-residency (afrag[2][4] = 64 regs, total ~128) and
// __launch_bounds__(256,4) targets 4 waves/SIMD; SPG 4->2 shrinks LDS to
// 34KB so 4 blocks/CU fit (136KB <= 160KB). Per-SIMD MFMA work per group
// unchanged (4 waves x 8 = 32), but 4 streams interleave + blocks desync.
// vmcnt ledger: stage_sp = 4 loads; prologue 8 out; each phase vmcnt(4)
// retires its own (FIFO-oldest) 4; stage(sp+2) restores 8; tail drains 0.
__global__ __launch_bounds__(256, 4) void entropy_kernel(
    const uint8_t* __restrict__ fbT,
    const float* __restrict__ sq, const float* __restrict__ temp,
    float* __restrict__ Sp, float* __restrict__ Tp)
{
    __shared__ uint4 buf[2][1024];                 // 2 x 16KB (2 groups x 8KB each)
    __shared__ float sqlds[NG * 16];               // pj inputs, off the vmem stream
    const int t    = threadIdx.x;
    const int w    = t >> 6;
    const int lane = t & 63;
    const int q    = lane >> 4;
    const int c16  = lane & 15;
    const int lbo  = lane * 16;

    const int flat  = blockIdx.x;
    const int combo = flat & 31;
    const int batch = combo >> 3;
    const int jh    = combo & 7;                   // == XCD id for L2 locality
    const int iblk  = flat >> 5;
    const int iw    = iblk * IPB + w * IPW;
    const size_t rowbase = (size_t)batch * N_TOK;

    const float tau    = temp[0];
    const float inv2t2 = 0.5f / (tau * tau);
    const float cg_    = 1.0f / (tau * tau);

    // A fragments from fbT (A/B per-lane layouts identical for 16x16x128)
    i32x8 afrag[2][4];
#pragma unroll
    for (int s = 0; s < 2; ++s) {
        const uint8_t* ga = fbT + ((rowbase + iw) / 16 + s) * 8192;
#pragma unroll
        for (int kk = 0; kk < 4; ++kk) {
            uint4 lo = *(const uint4*)(ga + kk * 2048 + lbo);
            uint4 hi = *(const uint4*)(ga + kk * 2048 + 1024 + lbo);
            i32x8 v = {(int)lo.x, (int)lo.y, (int)lo.z, (int)lo.w,
                       (int)hi.x, (int)hi.y, (int)hi.z, (int)hi.w};
            afrag[s][kk] = v;
        }
    }
    float pi_[2][4];
    float pim = -1e30f;                            // max_i pi, for the early-out
#pragma unroll
    for (int s = 0; s < 2; ++s) {
        float4 p4 = *(const float4*)(sq + rowbase + iw + s * 16 + q * 4);
        pi_[s][0] = -p4.x * inv2t2; pi_[s][1] = -p4.y * inv2t2;
        pi_[s][2] = -p4.z * inv2t2; pi_[s][3] = -p4.w * inv2t2;
        pim = fmaxf(pim, fmaxf(fmaxf(pi_[s][0], pi_[s][1]),
                               fmaxf(pi_[s][2], pi_[s][3])));
    }
    {   // preload the slice's sq values into LDS (512 floats = 2KB)
        const float* sqslice = sq + rowbase + (size_t)jh * (N_TOK / JSPLIT);
        sqlds[t]       = sqslice[t];
        sqlds[t + 256] = sqslice[t + 256];
    }

    float S[2][4], T[2][4];
#pragma unroll
    for (int s = 0; s < 2; ++s)
#pragma unroll
        for (int r = 0; r < 4; ++r) { S[s][r] = 0.f; T[s][r] = 0.f; }

    const uint8_t* bgbase = fbT
        + ((size_t)batch * (N_TOK / 16) + (size_t)jh * NG) * 8192;

    auto stage_sp = [&](int sp, int b) {           // wave w: its 2KB of each group
#pragma unroll
        for (int i = 0; i < SPG; ++i) {
            const uint8_t* gs = bgbase + ((size_t)sp * SPG + i) * 8192 + w * 2048 + lbo;
            uint8_t* ld = (uint8_t*)(&buf[b][0]) + i * 8192 + w * 2048;
            __builtin_amdgcn_global_load_lds((gptr_t)(const void*)gs,
                                             (lptr_t)(void*)ld, 16, 0, 0);
            __builtin_amdgcn_global_load_lds((gptr_t)(const void*)(gs + 1024),
                                             (lptr_t)(void*)(ld + 1024), 16, 0, 0);
        }
    };

    stage_sp(0, 0);
    stage_sp(1, 1);
    // one-time: sqlds visible to all waves (raw barrier keeps vmcnt ledger intact)
    asm volatile("s_waitcnt lgkmcnt(0)" ::: "memory");
    __builtin_amdgcn_s_barrier();

    for (int sp = 0; sp < NSP; ++sp) {
        if (sp < NSP - 1) asm volatile("s_waitcnt vmcnt(4)" ::: "memory");
        else              asm volatile("s_waitcnt vmcnt(0)" ::: "memory");
        __builtin_amdgcn_s_barrier();              // all waves' stage(sp) confirmed
        __builtin_amdgcn_sched_barrier(0);

        const uint8_t* sb = (const uint8_t*)(&buf[sp & 1][0]);
        __builtin_amdgcn_s_setprio(1);
#pragma unroll
        for (int i = 0; i < SPG; ++i) {            // un-fenced 2-group body
            const int g = sp * SPG + i;
            const uint8_t* bs = sb + i * 8192;
            float pj = -sqlds[g * 16 + c16] * inv2t2;
            f32x4 acc[2] = {{0,0,0,0},{0,0,0,0}};
#pragma unroll
            for (int kk = 0; kk < 4; ++kk) {
                uint4 lo = *(const uint4*)(bs + kk * 2048 + lbo);
                uint4 hi = *(const uint4*)(bs + kk * 2048 + 1024 + lbo);
                i32x8 b = {(int)lo.x, (int)lo.y, (int)lo.z, (int)lo.w,
                           (int)hi.x, (int)hi.y, (int)hi.z, (int)hi.w};
                acc[0] = __builtin_amdgcn_mfma_scale_f32_16x16x128_f8f6f4(afrag[0][kk], b, acc[0], 0, 0, 0, 127, 0, 127);
                acc[1] = __builtin_amdgcn_mfma_scale_f32_16x16x128_f8f6f4(afrag[1][kk], b, acc[1], 0, 0, 0, 127, 0, 127);
            }
            // early-out: bound >= true per-lane max of e; extra-taken groups add
            // exp(<=-110) == 0.0f exactly -> bit-identical to the full path.
            float m0 = fmaxf(fmaxf(acc[0][0], acc[0][1]), fmaxf(acc[0][2], acc[0][3]));
            float m1 = fmaxf(fmaxf(acc[1][0], acc[1][1]), fmaxf(acc[1][2], acc[1][3]));
            float mm = fmaxf(m0, m1);
            float bound = fmaf(mm, cg_, pim + pj);
            if (bound > -110.0f) {
#pragma unroll
                for (int s = 0; s < 2; ++s)
#pragma unroll
                    for (int r = 0; r < 4; ++r) {
                        float e  = fmaf(acc[s][r], cg_, pi_[s][r] + pj);
                        float ee = fminf(e, 0.f);
                        float k  = __expf(ee);
                        S[s][r] += k;
                        T[s][r]  = fmaf(k, ee, T[s][r]);
                    }
            }
        }
        __builtin_amdgcn_s_setprio(0);

        // seal own ds_reads of buf[sp&1]; barrier -> ALL waves sealed -> safe to
        // DMA-overwrite with superphase sp+2.
        asm volatile("s_waitcnt lgkmcnt(0)" ::: "memory");
        __builtin_amdgcn_s_barrier();
        __builtin_amdgcn_sched_barrier(0);
        if (sp + 2 < NSP) stage_sp(sp + 2, sp & 1);
    }

    // reduce over the 16 j-columns (c16 lanes)
#pragma unroll
    for (int m = 1; m < 16; m <<= 1)
#pragma unroll
        for (int s = 0; s < 2; ++s)
#pragma unroll
            for (int r = 0; r < 4; ++r) {
                S[s][r] += __shfl_xor(S[s][r], m);
                T[s][r] += __shfl_xor(T[s][r], m);
            }

    if (c16 == 0) {
#pragma unroll
        for (int s = 0; s < 2; ++s)
#pragma unroll
            for (int r = 0; r < 4; ++r) {
                size_t idx = (size_t)jh * BN + rowbase + iw + s * 16 + q * 4 + r;
                Sp[idx] = S[s][r];
                Tp[idx] = T[s][r];
            }
    }
}

// ---------- finalize: combine partials, entropy -> sigmoid -> scale features ----------
__global__ __launch_bounds__(256) void finalize_kernel(
    const float* __restrict__ feat, const float* __restrict__ Sp,
    const float* __restrict__ Tp, const float* __restrict__ tgt,
    const float* __restrict__ temp, float* __restrict__ out)
{
    int row  = (blockIdx.x << 2) + (threadIdx.x >> 6);   // global row 0..BN-1
    int lane = threadIdx.x & 63;
    float S = 0.0f, T = 0.0f;
#pragma unroll
    for (int j = 0; j < JSPLIT; ++j) {
        S += Sp[(size_t)j * BN + row];
        T += Tp[(size_t)j * BN + row];
    }
    float tau = temp[0];
    float E  = __logf(S) - T / S;                  // entropy (sans +1e-6, bias<4e-3)
    float cs = 1.0f / (1.0f + __expf((E - tgt[0]) / tau));

    const float4* F4 = (const float4*)(feat + (size_t)row * DIM);
    float4*       O4 = (float4*)(out + (size_t)row * DIM);
    float4 v0 = F4[lane], v1 = F4[lane + 64];
    v0.x *= cs; v0.y *= cs; v0.z *= cs; v0.w *= cs;
    v1.x *= cs; v1.y *= cs; v1.z *= cs; v1.w *= cs;
    O4[lane] = v0; O4[lane + 64] = v1;
    if (lane == 0) out[(size_t)BN * DIM + row] = cs;
}

extern "C" void kernel_launch(void* const* d_in, const int* in_sizes, int n_in,
                              void* d_out, int out_size, void* d_ws, size_t ws_size,
                              hipStream_t stream) {
    const float* feat = (const float*)d_in[0];
    const float* tgt  = (const float*)d_in[7];   // target_entropy
    const float* temp = (const float*)d_in[8];   // temperature
    float* out = (float*)d_out;

    char* ws = (char*)d_ws;
    uint8_t* fbT = (uint8_t*)ws;                               // fp8 operand-image, 8.4MB
    float*   sq  = (float*)(fbT + (size_t)BN * DIM);           // quantized row sumsq
    float*   Sp  = sq + BN;                                    // partial S, JSPLIT slices
    float*   Tp  = Sp + (size_t)JSPLIT * BN;                   // partial T, JSPLIT slices

    prep_kernel<<<dim3(BN / 16), dim3(256), 0, stream>>>(feat, fbT, sq);
    entropy_kernel<<<dim3((N_TOK / IPB) * BATCH * JSPLIT), dim3(256), 0, stream>>>(fbT, sq, temp, Sp, Tp);
    finalize_kernel<<<dim3(BN / 4), dim3(256), 0, stream>>>(feat, Sp, Tp, tgt, temp, out);
}

// Round 7
// 139.744 us; speedup vs baseline: 1.1285x; 1.0166x over previous
//
#include <hip/hip_runtime.h>
#include <stdint.h>

#define N_TOK 4096
#define DIM   512
#define BATCH 4
#define BN    (BATCH * N_TOK)
#define NSUP  16                      // 256-row super-tiles per batch
#define NPAIR 136                     // NSUP*(NSUP+1)/2 unordered pairs
#define IPW   64                      // i-rows per wave (A resident in regs)
#define IPB   256                     // i-rows per block (4 waves) = one super-tile
#define NG2   16                      // j-groups of 16 per super-tile
#define SPG   2                       // j-groups per superphase
#define NSP   (NG2 / SPG)             // 8 superphases

typedef __attribute__((ext_vector_type(4))) float f32x4;
typedef __attribute__((ext_vector_type(8))) int   i32x8;

typedef const __attribute__((address_space(1))) uint32_t* gptr_t;
typedef __attribute__((address_space(3))) uint32_t* lptr_t;

__device__ __forceinline__ float sumsq8(uint lo, uint hi) {
    float s = 0.f, f;
    f = __builtin_amdgcn_cvt_f32_fp8((int)lo, 0); s = fmaf(f, f, s);
    f = __builtin_amdgcn_cvt_f32_fp8((int)lo, 1); s = fmaf(f, f, s);
    f = __builtin_amdgcn_cvt_f32_fp8((int)lo, 2); s = fmaf(f, f, s);
    f = __builtin_amdgcn_cvt_f32_fp8((int)lo, 3); s = fmaf(f, f, s);
    f = __builtin_amdgcn_cvt_f32_fp8((int)hi, 0); s = fmaf(f, f, s);
    f = __builtin_amdgcn_cvt_f32_fp8((int)hi, 1); s = fmaf(f, f, s);
    f = __builtin_amdgcn_cvt_f32_fp8((int)hi, 2); s = fmaf(f, f, s);
    f = __builtin_amdgcn_cvt_f32_fp8((int)hi, 3); s = fmaf(f, f, s);
    return s;
}

// ---------- prep: fp8 convert -> fbT (operand-image layout; A and B per-lane MFMA
// layouts are identical for 16x16x128, so entropy reads BOTH operands from fbT)
// + per-row sumsq of QUANTIZED values (diag d_ii ~ 0 matches ref k_ii=1).
// fbT per 16-row group (8KB):
//   byte = kk*2048 + half*1024 + lane*16 + w8p*8, lane = q*16 + r
//   content = row r, K bytes [kk*128 + q*32 + (half*2+w8p)*8 .. +8)
__global__ __launch_bounds__(256) void prep_kernel(
    const float* __restrict__ feat, uint8_t* __restrict__ fbT,
    float* __restrict__ sq)
{
    __shared__ __align__(16) long lt[1024];        // [chunk c 0..63][row16], swizzled
    const int t = threadIdx.x;
    const int row16 = t >> 4, seg = t & 15;
    const size_t grp = blockIdx.x;
    const size_t row = grp * 16 + row16;

    const float4* src = (const float4*)(feat + row * DIM + seg * 32);
    uint32_t wd[8];
    float s = 0.f;
#pragma unroll
    for (int i = 0; i < 4; ++i) {
        float4 a = src[2 * i], b = src[2 * i + 1];
        uint lo = (uint)__builtin_amdgcn_cvt_pk_fp8_f32(a.x, a.y, 0, false);
        lo      = (uint)__builtin_amdgcn_cvt_pk_fp8_f32(a.z, a.w, (int)lo, true);
        uint hi = (uint)__builtin_amdgcn_cvt_pk_fp8_f32(b.x, b.y, 0, false);
        hi      = (uint)__builtin_amdgcn_cvt_pk_fp8_f32(b.z, b.w, (int)hi, true);
        wd[2 * i] = lo; wd[2 * i + 1] = hi;
        s += sumsq8(lo, hi);
    }

#pragma unroll
    for (int i = 0; i < 4; ++i) {
        int c = seg * 4 + i;                       // 8B chunk of this row
        long d = ((long)(unsigned)wd[2 * i + 1] << 32) | (unsigned)wd[2 * i];
        lt[c * 16 + ((row16 + c) & 15)] = d;
    }

#pragma unroll
    for (int m = 1; m < 16; m <<= 1) s += __shfl_xor(s, m);
    if (seg == 0) sq[row] = s;

    __syncthreads();
    long* ot = (long*)(fbT + grp * 8192);
#pragma unroll
    for (int i = 0; i < 4; ++i) {
        int p    = t + i * 256;                    // output long index, coalesced
        int kk   = p >> 8;                         // 128-wide K chunk
        int rem  = p & 255;
        int half = rem >> 7;                       // lo/hi 16B of the lane's 32B
        int l6   = (rem >> 1) & 63;                // dest lane
        int qq   = l6 >> 4;                        // 32-elem scale block
        int r    = l6 & 15;                        // j row in group
        int w8   = half * 2 + (p & 1);             // 8B word within lane's 32B
        int c    = kk * 16 + qq * 4 + w8;          // source 8B chunk in row
        ot[p] = lt[c * 16 + ((r + c) & 15)];
    }
}

// ---------- entropy: SYMMETRY-HALVED. Per batch, one block per unordered
// super-tile pair (a<=b) of 256 rows each: 136 tiles instead of 256 (53% of
// the MFMA work AND 53% of the group-instances — R4/R5/R6 showed per-group
// overhead is schedule- and occupancy-insensitive, so scale the group count).
// From tile (a,b): i-side row-sums over j (rows in a -> partial slot b) and
// j-side column-sums over i (rows in b -> partial slot a). Slot bijection
// (s>u: i-side of (u,s); s<u: j-side of (s,u); s==u: diagonal i-side) =>
// every [slot][row] written exactly once: deterministic, atomic-free, no init.
// j-side per group: per-lane ksum -> shfl over q -> per-wave LDS slot; global
// stores only after the main loop (counted-vmcnt ledger stays pure).
// Superphase schedule as R5: 2 groups per sync, un-fenced body, ledger:
// stage_sp = 4 loads; prologue 8 out; each phase vmcnt(4); tail vmcnt(0).
__global__ __launch_bounds__(256, 2) void entropy_kernel(
    const uint8_t* __restrict__ fbT,
    const float* __restrict__ sq, const float* __restrict__ temp,
    float* __restrict__ Sp, float* __restrict__ Tp)
{
    __shared__ uint4 buf[2][1024];                 // 2 x 16KB (2 groups x 8KB)
    __shared__ float sqlds[256];                   // j-slice sq (1KB)
    __shared__ float sjS[4][256];                  // per-wave j-side partials (4KB)
    __shared__ float sjT[4][256];                  // (4KB)
    const int t    = threadIdx.x;
    const int w    = t >> 6;
    const int lane = t & 63;
    const int q    = lane >> 4;
    const int c16  = lane & 15;
    const int lbo  = lane * 16;

    // decode (batch, pair) -> (a, b) with a <= b
    const int flat  = blockIdx.x;
    const int batch = flat / NPAIR;
    int rem = flat - batch * NPAIR;
    int aa = 0;
    while (rem >= NSUP - aa) { rem -= NSUP - aa; ++aa; }
    const int bb = aa + rem;
    const int iw    = aa * IPB + w * IPW;
    const int jbase = bb * IPB;
    const size_t rowbase = (size_t)batch * N_TOK;

    const float tau    = temp[0];
    const float inv2t2 = 0.5f / (tau * tau);
    const float cg_    = 1.0f / (tau * tau);

    // zero this wave's j-side slots (own-wave use only until final sync)
#pragma unroll
    for (int i = 0; i < 4; ++i) { sjS[w][lane * 4 + i] = 0.f; sjT[w][lane * 4 + i] = 0.f; }

    // A fragments from fbT (A/B per-lane layouts identical for 16x16x128)
    i32x8 afrag[4][4];
#pragma unroll
    for (int s = 0; s < 4; ++s) {
        const uint8_t* ga = fbT + ((rowbase + iw) / 16 + s) * 8192;
#pragma unroll
        for (int kk = 0; kk < 4; ++kk) {
            uint4 lo = *(const uint4*)(ga + kk * 2048 + lbo);
            uint4 hi = *(const uint4*)(ga + kk * 2048 + 1024 + lbo);
            i32x8 v = {(int)lo.x, (int)lo.y, (int)lo.z, (int)lo.w,
                       (int)hi.x, (int)hi.y, (int)hi.z, (int)hi.w};
            afrag[s][kk] = v;
        }
    }
    float pi_[4][4];
    float pim = -1e30f;                            // max_i pi, for the early-out
#pragma unroll
    for (int s = 0; s < 4; ++s) {
        float4 p4 = *(const float4*)(sq + rowbase + iw + s * 16 + q * 4);
        pi_[s][0] = -p4.x * inv2t2; pi_[s][1] = -p4.y * inv2t2;
        pi_[s][2] = -p4.z * inv2t2; pi_[s][3] = -p4.w * inv2t2;
        pim = fmaxf(pim, fmaxf(fmaxf(pi_[s][0], pi_[s][1]),
                               fmaxf(pi_[s][2], pi_[s][3])));
    }
    // preload the j-super's sq values into LDS (256 floats)
    sqlds[t] = sq[rowbase + jbase + t];

    float S[4][4], T[4][4];
#pragma unroll
    for (int s = 0; s < 4; ++s)
#pragma unroll
        for (int r = 0; r < 4; ++r) { S[s][r] = 0.f; T[s][r] = 0.f; }

    const uint8_t* bgbase = fbT
        + ((size_t)batch * (N_TOK / 16) + (size_t)(jbase / 16)) * 8192;

    auto stage_sp = [&](int sp, int b) {           // wave w: its 2KB of each group
#pragma unroll
        for (int i = 0; i < SPG; ++i) {
            const uint8_t* gs = bgbase + ((size_t)sp * SPG + i) * 8192 + w * 2048 + lbo;
            uint8_t* ld = (uint8_t*)(&buf[b][0]) + i * 8192 + w * 2048;
            __builtin_amdgcn_global_load_lds((gptr_t)(const void*)gs,
                                             (lptr_t)(void*)ld, 16, 0, 0);
            __builtin_amdgcn_global_load_lds((gptr_t)(const void*)(gs + 1024),
                                             (lptr_t)(void*)(ld + 1024), 16, 0, 0);
        }
    };

    stage_sp(0, 0);
    stage_sp(1, 1);
    // one-time: sqlds visible to all waves (raw barrier keeps vmcnt ledger intact)
    asm volatile("s_waitcnt lgkmcnt(0)" ::: "memory");
    __builtin_amdgcn_s_barrier();

    for (int sp = 0; sp < NSP; ++sp) {
        if (sp < NSP - 1) asm volatile("s_waitcnt vmcnt(4)" ::: "memory");
        else              asm volatile("s_waitcnt vmcnt(0)" ::: "memory");
        __builtin_amdgcn_s_barrier();              // all waves' stage(sp) confirmed
        __builtin_amdgcn_sched_barrier(0);

        const uint8_t* sb = (const uint8_t*)(&buf[sp & 1][0]);
        __builtin_amdgcn_s_setprio(1);
#pragma unroll
        for (int i = 0; i < SPG; ++i) {            // un-fenced 2-group body
            const int g = sp * SPG + i;
            const uint8_t* bs = sb + i * 8192;
            float pj = -sqlds[g * 16 + c16] * inv2t2;
            f32x4 acc[4] = {{0,0,0,0},{0,0,0,0},{0,0,0,0},{0,0,0,0}};
#pragma unroll
            for (int kk = 0; kk < 4; ++kk) {
                uint4 lo = *(const uint4*)(bs + kk * 2048 + lbo);
                uint4 hi = *(const uint4*)(bs + kk * 2048 + 1024 + lbo);
                i32x8 b = {(int)lo.x, (int)lo.y, (int)lo.z, (int)lo.w,
                           (int)hi.x, (int)hi.y, (int)hi.z, (int)hi.w};
                acc[0] = __builtin_amdgcn_mfma_scale_f32_16x16x128_f8f6f4(afrag[0][kk], b, acc[0], 0, 0, 0, 127, 0, 127);
                acc[1] = __builtin_amdgcn_mfma_scale_f32_16x16x128_f8f6f4(afrag[1][kk], b, acc[1], 0, 0, 0, 127, 0, 127);
                acc[2] = __builtin_amdgcn_mfma_scale_f32_16x16x128_f8f6f4(afrag[2][kk], b, acc[2], 0, 0, 0, 127, 0, 127);
                acc[3] = __builtin_amdgcn_mfma_scale_f32_16x16x128_f8f6f4(afrag[3][kk], b, acc[3], 0, 0, 0, 127, 0, 127);
            }
            // wave-uniform early-out (needed: j-side shfl must be non-divergent).
            // Skipped groups' k = exp(<=-110) == 0.0f exactly -> bit-identical,
            // and their sj slots keep the pre-zeroed 0.0f.
            float m0 = fmaxf(fmaxf(acc[0][0], acc[0][1]), fmaxf(acc[0][2], acc[0][3]));
            float m1 = fmaxf(fmaxf(acc[1][0], acc[1][1]), fmaxf(acc[1][2], acc[1][3]));
            float m2 = fmaxf(fmaxf(acc[2][0], acc[2][1]), fmaxf(acc[2][2], acc[2][3]));
            float m3 = fmaxf(fmaxf(acc[3][0], acc[3][1]), fmaxf(acc[3][2], acc[3][3]));
            float mm = fmaxf(fmaxf(m0, m1), fmaxf(m2, m3));
            float bound = fmaf(mm, cg_, pim + pj);
            if (__any(bound > -110.0f)) {
                float ks = 0.f, kt = 0.f;
#pragma unroll
                for (int s = 0; s < 4; ++s)
#pragma unroll
                    for (int r = 0; r < 4; ++r) {
                        float e   = fmaf(acc[s][r], cg_, pi_[s][r] + pj);
                        float ee  = fminf(e, 0.f);
                        float k   = __expf(ee);
                        float kei = k * ee;
                        S[s][r] += k;  T[s][r] += kei;
                        ks      += k;  kt      += kei;
                    }
                if (aa != bb) {                    // j-side: reduce over the wave's 64 i
                    ks += __shfl_xor(ks, 16); ks += __shfl_xor(ks, 32);
                    kt += __shfl_xor(kt, 16); kt += __shfl_xor(kt, 32);
                    if (lane < 16) {
                        sjS[w][g * 16 + lane] = ks;
                        sjT[w][g * 16 + lane] = kt;
                    }
                }
            }
        }
        __builtin_amdgcn_s_setprio(0);

        // seal own ds_reads of buf[sp&1]; barrier -> ALL waves sealed -> safe to
        // DMA-overwrite with superphase sp+2.
        asm volatile("s_waitcnt lgkmcnt(0)" ::: "memory");
        __builtin_amdgcn_s_barrier();
        __builtin_amdgcn_sched_barrier(0);
        if (sp + 2 < NSP) stage_sp(sp + 2, sp & 1);
    }

    // ---- i-side: reduce over the 16 j-columns (c16 lanes), write slot bb ----
#pragma unroll
    for (int m = 1; m < 16; m <<= 1)
#pragma unroll
        for (int s = 0; s < 4; ++s)
#pragma unroll
            for (int r = 0; r < 4; ++r) {
                S[s][r] += __shfl_xor(S[s][r], m);
                T[s][r] += __shfl_xor(T[s][r], m);
            }
    if (c16 == 0) {
#pragma unroll
        for (int s = 0; s < 4; ++s)
#pragma unroll
            for (int r = 0; r < 4; ++r) {
                size_t idx = (size_t)bb * BN + rowbase + iw + s * 16 + q * 4 + r;
                Sp[idx] = S[s][r];
                Tp[idx] = T[s][r];
            }
    }

    // ---- j-side: combine the 4 waves' partials, write slot aa (rows in b) ----
    if (aa != bb) {
        __syncthreads();                           // all waves' sj writes visible
        float s4 = sjS[0][t] + sjS[1][t] + sjS[2][t] + sjS[3][t];
        float t4 = sjT[0][t] + sjT[1][t] + sjT[2][t] + sjT[3][t];
        size_t idx = (size_t)aa * BN + rowbase + jbase + t;
        Sp[idx] = s4;
        Tp[idx] = t4;
    }
}

// ---------- finalize: combine 16 partial slots, entropy -> sigmoid -> scale ----------
__global__ __launch_bounds__(256) void finalize_kernel(
    const float* __restrict__ feat, const float* __restrict__ Sp,
    const float* __restrict__ Tp, const float* __restrict__ tgt,
    const float* __restrict__ temp, float* __restrict__ out)
{
    int row  = (blockIdx.x << 2) + (threadIdx.x >> 6);   // global row 0..BN-1
    int lane = threadIdx.x & 63;
    float S = 0.0f, T = 0.0f;
#pragma unroll
    for (int j = 0; j < NSUP; ++j) {
        S += Sp[(size_t)j * BN + row];
        T += Tp[(size_t)j * BN + row];
    }
    float tau = temp[0];
    float E  = __logf(S) - T / S;                  // entropy (sans +1e-6, bias<4e-3)
    float cs = 1.0f / (1.0f + __expf((E - tgt[0]) / tau));

    const float4* F4 = (const float4*)(feat + (size_t)row * DIM);
    float4*       O4 = (float4*)(out + (size_t)row * DIM);
    float4 v0 = F4[lane], v1 = F4[lane + 64];
    v0.x *= cs; v0.y *= cs; v0.z *= cs; v0.w *= cs;
    v1.x *= cs; v1.y *= cs; v1.z *= cs; v1.w *= cs;
    O4[lane] = v0; O4[lane + 64] = v1;
    if (lane == 0) out[(size_t)BN * DIM + row] = cs;
}

extern "C" void kernel_launch(void* const* d_in, const int* in_sizes, int n_in,
                              void* d_out, int out_size, void* d_ws, size_t ws_size,
                              hipStream_t stream) {
    const float* feat = (const float*)d_in[0];
    const float* tgt  = (const float*)d_in[7];   // target_entropy
    const float* temp = (const float*)d_in[8];   // temperature
    float* out = (float*)d_out;

    char* ws = (char*)d_ws;
    uint8_t* fbT = (uint8_t*)ws;                               // fp8 operand-image, 8.4MB
    float*   sq  = (float*)(fbT + (size_t)BN * DIM);           // quantized row sumsq
    float*   Sp  = sq + BN;                                    // partial S, NSUP slots
    float*   Tp  = Sp + (size_t)NSUP * BN;                     // partial T, NSUP slots

    prep_kernel<<<dim3(BN / 16), dim3(256), 0, stream>>>(feat, fbT, sq);
    entropy_kernel<<<dim3(BATCH * NPAIR), dim3(256), 0, stream>>>(fbT, sq, temp, Sp, Tp);
    finalize_kernel<<<dim3(BN / 4), dim3(256), 0, stream>>>(feat, Sp, Tp, tgt, temp, out);
}